// Round 2
// baseline (1813.422 us; speedup 1.0000x reference)
//
#include <hip/hip_runtime.h>
#include <stdint.h>

typedef float    f32x4 __attribute__((ext_vector_type(4)));
typedef float    f32x2 __attribute__((ext_vector_type(2)));
typedef _Float16 f16x8 __attribute__((ext_vector_type(8)));
typedef _Float16 f16x4 __attribute__((ext_vector_type(4)));
typedef _Float16 f16x2 __attribute__((ext_vector_type(2)));

#define SEQ   2048
#define HIDD  2048
#define MROWS 4096
#define NQKV  12288          // 96 tiles of 128, no pad

__device__ __forceinline__ void gload_lds16(const void* g, void* l) {
  __builtin_amdgcn_global_load_lds((const __attribute__((address_space(1))) uint32_t*)g,
                                   (__attribute__((address_space(3))) uint32_t*)l, 16, 0, 0);
}

// ---------------- A = (h * mask) -> fp16 ----------------
__global__ __launch_bounds__(256)
void amask_kernel(const float* __restrict__ h, const float* __restrict__ mask,
                  _Float16* __restrict__ A1) {
  int i = blockIdx.x * 256 + threadIdx.x;            // one float4 each
  if (i >= MROWS * HIDD / 4) return;
  f32x4 x = ((const f32x4*)h)[i];
  float m = mask[(i * 4) >> 11];
  f16x4 r;
  r[0] = (_Float16)(x[0] * m); r[1] = (_Float16)(x[1] * m);
  r[2] = (_Float16)(x[2] * m); r[3] = (_Float16)(x[3] * m);
  *(f16x4*)(A1 + (size_t)i * 4) = r;
}

// ---------------- transpose fp32 [R][C] -> fp16 [C][R] ----------------
__global__ __launch_bounds__(256)
void transpose_f16(const float* __restrict__ in, _Float16* __restrict__ out,
                   int R, int C) {
  __shared__ float tile[64][65];
  int c0 = blockIdx.x * 64, r0 = blockIdx.y * 64;
  int tx = threadIdx.x & 63, ty = threadIdx.x >> 6;
  #pragma unroll
  for (int i = 0; i < 16; ++i) {
    int r = i * 4 + ty;
    tile[r][tx] = in[(size_t)(r0 + r) * C + c0 + tx];
  }
  __syncthreads();
  #pragma unroll
  for (int i = 0; i < 16; ++i) {
    int c = i * 4 + ty;
    out[(size_t)(c0 + c) * R + r0 + tx] = (_Float16)tile[tx][c];
  }
}

// ---------------- fp16 MFMA GEMM: C[M][N] = A[M][K] * Bt[N][K]^T ----------------
template <typename CT>
__global__ __launch_bounds__(256, 2)
void gemm_f16(const _Float16* __restrict__ A, const _Float16* __restrict__ Bt,
              CT* __restrict__ C, int M, int N, int K, int tiles_n) {
  __shared__ _Float16 lsA[128 * 32];
  __shared__ _Float16 lsB[128 * 32];
  int bm = blockIdx.x / tiles_n, bn = blockIdx.x % tiles_n;
  int m0 = bm * 128, n0 = bn * 128;
  int lane = threadIdx.x & 63, wid = threadIdx.x >> 6;
  int wr = wid >> 1, wc = wid & 1;
  int la = lane & 15, lk = lane >> 4;
  int ldrow = lane >> 2;          // 0..15
  int ldcol = (lane & 3) * 8;     // 8 halves = 16B
  f32x4 acc[4][4] = {};
  for (int k0 = 0; k0 < K; k0 += 32) {
    __syncthreads();
    #pragma unroll
    for (int si = 0; si < 2; ++si) {
      int seg = wid * 2 + si;               // 0..7, 16 rows each
      int row = seg * 16 + ldrow;
      gload_lds16(A  + (size_t)(m0 + row) * K + k0 + ldcol, &lsA[seg * 512]);
      gload_lds16(Bt + (size_t)(n0 + row) * K + k0 + ldcol, &lsB[seg * 512]);
    }
    __syncthreads();
    f16x8 af[4], bf[4];
    #pragma unroll
    for (int f = 0; f < 4; ++f) {
      af[f] = *(const f16x8*)&lsA[(wr * 64 + f * 16 + la) * 32 + lk * 8];
      bf[f] = *(const f16x8*)&lsB[(wc * 64 + f * 16 + la) * 32 + lk * 8];
    }
    #pragma unroll
    for (int i = 0; i < 4; ++i)
      #pragma unroll
      for (int j = 0; j < 4; ++j)
        acc[i][j] = __builtin_amdgcn_mfma_f32_16x16x32_f16(af[i], bf[j], acc[i][j], 0, 0, 0);
  }
  #pragma unroll
  for (int i = 0; i < 4; ++i)
    #pragma unroll
    for (int j = 0; j < 4; ++j) {
      int col = n0 + wc * 64 + j * 16 + la;
      #pragma unroll
      for (int r = 0; r < 4; ++r) {
        int row = m0 + wr * 64 + i * 16 + lk * 4 + r;
        C[(size_t)row * N + col] = (CT)acc[i][j][r];
      }
    }
}

// ---------------- ba = (h*mask) @ W_ba in fp32 (precision-critical for g) ----------------
__global__ __launch_bounds__(256)
void ba_gemm(const float* __restrict__ h, const float* __restrict__ mask,
             const float* __restrict__ Wba, float* __restrict__ ba) {
  __shared__ float red[4][8][64];
  int r0 = blockIdx.x * 8;
  int c = threadIdx.x & 63, kc = threadIdx.x >> 6;
  float acc[8] = {};
  const float* wp = Wba + (size_t)(kc * 512) * 64 + c;
  const float* hp = h + (size_t)r0 * HIDD + kc * 512;
  for (int i = 0; i < 512; ++i) {
    float w = wp[(size_t)i * 64];
    #pragma unroll
    for (int r = 0; r < 8; ++r)
      acc[r] += hp[(size_t)r * HIDD + i] * w;
  }
  #pragma unroll
  for (int r = 0; r < 8; ++r) red[kc][r][c] = acc[r];
  __syncthreads();
  if (kc == 0) {
    #pragma unroll
    for (int r = 0; r < 8; ++r) {
      float s = red[0][r][c] + red[1][r][c] + red[2][r][c] + red[3][r][c];
      ba[(size_t)(r0 + r) * 64 + c] = s * mask[r0 + r];
    }
  }
}

// ---------------- conv(4-tap causal) + SiLU + l2norm -> qn16, kn16, vb16 ----------------
__global__ __launch_bounds__(256)
void conv_kernel(const _Float16* __restrict__ qkvz, const float* __restrict__ ck,
                 _Float16* __restrict__ qn, _Float16* __restrict__ kn,
                 _Float16* __restrict__ vb) {
  int row = blockIdx.x;               // b*2048 + t
  int b = row >> 11, t = row & 2047;
  int lane = threadIdx.x & 63, wid = threadIdx.x >> 6;
  for (int u = wid; u < 64; u += 4) {
    int c, cc, hh;
    if (u < 16)      { hh = u;      c = hh * 768;                               cc = hh * 128; }
    else if (u < 32) { hh = u - 16; c = hh * 768 + 128;                         cc = 2048 + hh * 128; }
    else             { hh = u - 32; c = (hh >> 1) * 768 + 256 + (hh & 1) * 128; cc = 4096 + hh * 128; }
    float y0 = 0.f, y1 = 0.f;
    #pragma unroll
    for (int j = 0; j < 4; ++j) {
      int tt = t - 3 + j;
      if (tt >= 0) {
        const _Float16* r = qkvz + (size_t)(b * 2048 + tt) * NQKV + c;
        f16x2 x = *(const f16x2*)(r + 2 * lane);
        f32x2 w = *(const f32x2*)(ck + j * 8192 + cc + 2 * lane);
        y0 += (float)x[0] * w[0];
        y1 += (float)x[1] * w[1];
      }
    }
    y0 = y0 / (1.f + expf(-y0));
    y1 = y1 / (1.f + expf(-y1));
    if (u < 32) {
      float ss = y0 * y0 + y1 * y1;
      #pragma unroll
      for (int m = 1; m < 64; m <<= 1) ss += __shfl_xor(ss, m);
      float rs = rsqrtf(ss + 1e-6f);
      if (u < 16) rs *= 0.08838834764831845f;   // DK^-0.5
      y0 *= rs; y1 *= rs;
      _Float16* dst = (u < 16 ? qn : kn) + (size_t)row * 2048 + hh * 128;
      f16x2 o; o[0] = (_Float16)y0; o[1] = (_Float16)y1;
      *(f16x2*)(dst + 2 * lane) = o;
    } else {
      _Float16* dst = vb + (size_t)row * 4096 + hh * 128;
      f16x2 o; o[0] = (_Float16)y0; o[1] = (_Float16)y1;
      *(f16x2*)(dst + 2 * lane) = o;
    }
  }
}

// ---------------- g/beta from fp32 ba ----------------
__global__ __launch_bounds__(256)
void egbeta_kernel(const float* __restrict__ ba, const float* __restrict__ Alog,
                   const float* __restrict__ dtb, float* __restrict__ eg,
                   float* __restrict__ bet) {
  int i = blockIdx.x * 256 + threadIdx.x;     // MROWS*32
  if (i >= MROWS * 32) return;
  int row = i >> 5, vh = i & 31;
  int kh = vh >> 1, r = vh & 1;
  const float* p = ba + (size_t)row * 64 + kh * 4;
  float bv = p[r], av = p[2 + r];
  float x = av + dtb[vh];
  float sp = (x > 20.f) ? x : log1pf(expf(x));
  eg[i]  = expf(-expf(Alog[vh]) * sp);
  bet[i] = 1.f / (1.f + expf(-bv));
}

// ---------------- gated delta-rule scan (o written in-place into vb) ----------------
// block = 1 wave, owns (b, vh, 16 v-cols). lane = (kq 0..3, vc 0..15);
// lane holds S[kq*32 .. +31][vcol] in 32 VGPRs.
__global__ __launch_bounds__(64, 1)
void scan_kernel(const _Float16* __restrict__ qn, const _Float16* __restrict__ kn,
                 _Float16* __restrict__ vb, const float* __restrict__ eg,
                 const float* __restrict__ bet) {
  __shared__ float kbuf[32 * 128];
  __shared__ float qbuf[32 * 128];
  __shared__ float vbuf[32 * 16];
  __shared__ float ebuf[32];
  __shared__ float bbuf[32];
  int bid = blockIdx.x;
  int b = bid >> 8, vh = (bid >> 3) & 31, vg = bid & 7;
  int kh = vh >> 1;
  int lane = threadIdx.x;
  int kq = lane >> 4, vc = lane & 15;
  float s[32];
  #pragma unroll
  for (int i = 0; i < 32; ++i) s[i] = 0.f;
  const _Float16* kb  = kn + (size_t)b * SEQ * 2048 + kh * 128;
  const _Float16* qb  = qn + (size_t)b * SEQ * 2048 + kh * 128;
  _Float16*       vbm = vb + (size_t)b * SEQ * 4096 + vh * 128 + vg * 16;
  const float* ebase = eg  + (size_t)b * SEQ * 32 + vh;
  const float* bbase = bet + (size_t)b * SEQ * 32 + vh;
  int row2 = lane >> 1, hsel = lane & 1;
  for (int t0 = 0; t0 < SEQ; t0 += 32) {
    // reg-stage fp16 -> fp32 LDS
    #pragma unroll
    for (int j = 0; j < 8; ++j) {
      f16x8 kv = *(const f16x8*)(kb + (size_t)(t0 + row2) * 2048 + hsel * 64 + j * 8);
      f16x8 qv = *(const f16x8*)(qb + (size_t)(t0 + row2) * 2048 + hsel * 64 + j * 8);
      int idx = row2 * 128 + hsel * 64 + j * 8;
      f32x4 lo, hi;
      lo[0] = (float)kv[0]; lo[1] = (float)kv[1]; lo[2] = (float)kv[2]; lo[3] = (float)kv[3];
      hi[0] = (float)kv[4]; hi[1] = (float)kv[5]; hi[2] = (float)kv[6]; hi[3] = (float)kv[7];
      *(f32x4*)&kbuf[idx] = lo; *(f32x4*)&kbuf[idx + 4] = hi;
      lo[0] = (float)qv[0]; lo[1] = (float)qv[1]; lo[2] = (float)qv[2]; lo[3] = (float)qv[3];
      hi[0] = (float)qv[4]; hi[1] = (float)qv[5]; hi[2] = (float)qv[6]; hi[3] = (float)qv[7];
      *(f32x4*)&qbuf[idx] = lo; *(f32x4*)&qbuf[idx + 4] = hi;
    }
    {
      f16x8 vv = *(const f16x8*)(vbm + (size_t)(t0 + row2) * 4096 + hsel * 8);
      int idx = row2 * 16 + hsel * 8;
      f32x4 lo, hi;
      lo[0] = (float)vv[0]; lo[1] = (float)vv[1]; lo[2] = (float)vv[2]; lo[3] = (float)vv[3];
      hi[0] = (float)vv[4]; hi[1] = (float)vv[5]; hi[2] = (float)vv[6]; hi[3] = (float)vv[7];
      *(f32x4*)&vbuf[idx] = lo; *(f32x4*)&vbuf[idx + 4] = hi;
    }
    if (lane < 32) {
      ebuf[lane] = ebase[(size_t)(t0 + lane) * 32];
      bbuf[lane] = bbase[(size_t)(t0 + lane) * 32];
    }
    __syncthreads();
    for (int t = 0; t < 32; ++t) {
      const float* kp = &kbuf[t * 128 + kq * 32];
      f32x4 kf[8];
      #pragma unroll
      for (int i = 0; i < 8; ++i) kf[i] = *(const f32x4*)(kp + i * 4);
      float pa = 0.f, pb = 0.f, pc = 0.f, pd = 0.f;
      #pragma unroll
      for (int i = 0; i < 8; ++i) {
        pa += kf[i][0] * s[4 * i + 0]; pb += kf[i][1] * s[4 * i + 1];
        pc += kf[i][2] * s[4 * i + 2]; pd += kf[i][3] * s[4 * i + 3];
      }
      float p = (pa + pb) + (pc + pd);
      p += __shfl_xor(p, 16);
      p += __shfl_xor(p, 32);
      float egt = ebuf[t], btt = bbuf[t];
      float delta = (vbuf[t * 16 + vc] - egt * p) * btt;   // kv uses decayed S
      const float* qp = &qbuf[t * 128 + kq * 32];
      float oa = 0.f, ob = 0.f, oc = 0.f, od = 0.f;
      #pragma unroll
      for (int i = 0; i < 8; ++i) {
        f32x4 q4 = *(const f32x4*)(qp + i * 4);
        float u0 = kf[i][0] * delta; s[4*i+0] = fmaf(s[4*i+0], egt, u0); oa += q4[0] * s[4*i+0];
        float u1 = kf[i][1] * delta; s[4*i+1] = fmaf(s[4*i+1], egt, u1); ob += q4[1] * s[4*i+1];
        float u2 = kf[i][2] * delta; s[4*i+2] = fmaf(s[4*i+2], egt, u2); oc += q4[2] * s[4*i+2];
        float u3 = kf[i][3] * delta; s[4*i+3] = fmaf(s[4*i+3], egt, u3); od += q4[3] * s[4*i+3];
      }
      float oo = (oa + ob) + (oc + od);
      oo += __shfl_xor(oo, 16);
      oo += __shfl_xor(oo, 32);
      if (lane < 16) vbm[(size_t)(t0 + t) * 4096 + vc] = (_Float16)oo;  // in-place: v[t] dead
    }
    __syncthreads();
  }
}

// ---------------- RMSNorm * norm_kernel * silu(z) -> fp16 Ag ----------------
__global__ __launch_bounds__(256)
void gate_kernel(const _Float16* __restrict__ ob, const _Float16* __restrict__ qkvz,
                 const float* __restrict__ nk, _Float16* __restrict__ Ag) {
  int row = blockIdx.x;
  int lane = threadIdx.x & 63, wid = threadIdx.x >> 6;
  for (int vh = wid; vh < 32; vh += 4) {
    const _Float16* op = ob + (size_t)row * 4096 + vh * 128;
    f16x2 xx = *(const f16x2*)(op + 2 * lane);
    float x0 = (float)xx[0], x1 = (float)xx[1];
    float ss = x0 * x0 + x1 * x1;
    #pragma unroll
    for (int m = 1; m < 64; m <<= 1) ss += __shfl_xor(ss, m);
    float rs = rsqrtf(ss * (1.f / 128.f) + 1e-6f);
    f32x2 nv = *(const f32x2*)(nk + 2 * lane);
    float v0 = x0 * rs * nv[0], v1 = x1 * rs * nv[1];
    const _Float16* zp = qkvz + (size_t)row * NQKV + (vh >> 1) * 768 + 512 + (vh & 1) * 128;
    f16x2 zz = *(const f16x2*)(zp + 2 * lane);
    float z0 = (float)zz[0], z1 = (float)zz[1];
    v0 *= z0 / (1.f + expf(-z0));
    v1 *= z1 / (1.f + expf(-z1));
    _Float16* dst = Ag + (size_t)row * 4096 + vh * 128;
    f16x2 o; o[0] = (_Float16)v0; o[1] = (_Float16)v1;
    *(f16x2*)(dst + 2 * lane) = o;
  }
}

extern "C" void kernel_launch(void* const* d_in, const int* in_sizes, int n_in,
                              void* d_out, int out_size, void* d_ws, size_t ws_size,
                              hipStream_t stream) {
  const float* h     = (const float*)d_in[0];
  const float* mask  = (const float*)d_in[1];
  const float* Wqkvz = (const float*)d_in[2];
  const float* Wba   = (const float*)d_in[3];
  const float* ck    = (const float*)d_in[4];
  const float* Alog  = (const float*)d_in[5];
  const float* dtb   = (const float*)d_in[6];
  const float* nk    = (const float*)d_in[7];
  const float* Wout  = (const float*)d_in[8];
  float* out = (float*)d_out;

  char* w = (char*)d_ws;
  // arena layout (bytes); lifetimes allow heavy aliasing
  const size_t o_qkvz = 0;                         // 100,663,296  [gemm1 .. gate]
  const size_t o_A1   = 100663296;                 //  16,777,216  [amask .. gemm1]
  const size_t o_Bt1  = o_A1 + 16777216;           //  50,331,648  [transpose .. gemm1]
  const size_t o_ba   = o_Bt1 + 50331648;          //   1,048,576
  const size_t o_eg   = o_ba + 1048576;            //     524,288
  const size_t o_bt   = o_eg + 524288;             //     524,288
  const size_t total  = o_bt + 524288;             // 169,869,312 B = 162 MiB
  if (ws_size < total) return;

  _Float16* qkvz16 = (_Float16*)(w + o_qkvz);
  _Float16* A1     = (_Float16*)(w + o_A1);
  _Float16* Bt1    = (_Float16*)(w + o_Bt1);
  float*    ba32   = (float*)   (w + o_ba);
  float*    egb    = (float*)   (w + o_eg);
  float*    btb    = (float*)   (w + o_bt);
  // aliases over dead regions:
  _Float16* qn16 = (_Float16*)(w + o_A1);                    // over A1 (dead after gemm1)
  _Float16* kn16 = (_Float16*)(w + o_Bt1);                   // over Bt1[0:16M)
  _Float16* vb16 = (_Float16*)(w + o_Bt1 + 16777216);        // over Bt1[16M:50M); o in-place
  _Float16* Ag   = (_Float16*)(w + o_A1);                    // over qn+kn (dead after scan)
  _Float16* Wt2  = (_Float16*)(w + 0);                       // over qkvz (dead after gate)

  amask_kernel<<<MROWS * HIDD / 4 / 256, 256, 0, stream>>>(h, mask, A1);
  transpose_f16<<<dim3(192, 32), 256, 0, stream>>>(Wqkvz, Bt1, HIDD, NQKV);
  ba_gemm<<<MROWS / 8, 256, 0, stream>>>(h, mask, Wba, ba32);
  gemm_f16<_Float16><<<32 * 96, 256, 0, stream>>>(A1, Bt1, qkvz16, MROWS, NQKV, HIDD, 96);
  conv_kernel<<<MROWS, 256, 0, stream>>>(qkvz16, ck, qn16, kn16, vb16);
  egbeta_kernel<<<MROWS * 32 / 256, 256, 0, stream>>>(ba32, Alog, dtb, egb, btb);
  scan_kernel<<<512, 64, 0, stream>>>(qn16, kn16, vb16, egb, btb);
  gate_kernel<<<MROWS, 256, 0, stream>>>(vb16, qkvz16, nk, Ag);
  transpose_f16<<<dim3(32, 64), 256, 0, stream>>>(Wout, Wt2, 4096, HIDD);
  gemm_f16<float><<<32 * 16, 256, 0, stream>>>(Ag, Wt2, out, MROWS, HIDD, 4096, 16);
}

// Round 3
// 1111.825 us; speedup vs baseline: 1.6310x; 1.6310x over previous
//
#include <hip/hip_runtime.h>
#include <stdint.h>

typedef float    f32x4 __attribute__((ext_vector_type(4)));
typedef float    f32x2 __attribute__((ext_vector_type(2)));
typedef _Float16 f16x8 __attribute__((ext_vector_type(8)));
typedef _Float16 f16x4 __attribute__((ext_vector_type(4)));
typedef _Float16 f16x2 __attribute__((ext_vector_type(2)));

#define SEQ   2048
#define HIDD  2048
#define MROWS 4096
#define NQKV  12288          // 96 tiles of 128, no pad

__device__ __forceinline__ void gload_lds16(const void* g, void* l) {
  __builtin_amdgcn_global_load_lds((const __attribute__((address_space(1))) uint32_t*)g,
                                   (__attribute__((address_space(3))) uint32_t*)l, 16, 0, 0);
}
__device__ __forceinline__ void gload_lds4(const void* g, void* l) {
  __builtin_amdgcn_global_load_lds((const __attribute__((address_space(1))) uint32_t*)g,
                                   (__attribute__((address_space(3))) uint32_t*)l, 4, 0, 0);
}

// DPP butterfly add over 16 contiguous lanes (VALU pipe, no DS ops)
template<int CTRL>
__device__ __forceinline__ float dppadd(float x) {
  int y = __builtin_amdgcn_update_dpp(0, __builtin_bit_cast(int, x), CTRL, 0xF, 0xF, true);
  return x + __builtin_bit_cast(float, y);
}
__device__ __forceinline__ float rsum16(float x) {
  x = dppadd<0xB1>(x);    // quad_perm [1,0,3,2]  (xor1)
  x = dppadd<0x4E>(x);    // quad_perm [2,3,0,1]  (xor2)
  x = dppadd<0x141>(x);   // row_half_mirror      (crosses quads within 8)
  x = dppadd<0x140>(x);   // row_mirror           (crosses 8s within 16)
  return x;
}

// ---------------- A = (h * mask) -> fp16 ----------------
__global__ __launch_bounds__(256)
void amask_kernel(const float* __restrict__ h, const float* __restrict__ mask,
                  _Float16* __restrict__ A1) {
  int i = blockIdx.x * 256 + threadIdx.x;            // one float4 each
  if (i >= MROWS * HIDD / 4) return;
  f32x4 x = ((const f32x4*)h)[i];
  float m = mask[(i * 4) >> 11];
  f16x4 r;
  r[0] = (_Float16)(x[0] * m); r[1] = (_Float16)(x[1] * m);
  r[2] = (_Float16)(x[2] * m); r[3] = (_Float16)(x[3] * m);
  *(f16x4*)(A1 + (size_t)i * 4) = r;
}

// ---------------- transpose fp32 [R][C] -> fp16 [C][R] ----------------
__global__ __launch_bounds__(256)
void transpose_f16(const float* __restrict__ in, _Float16* __restrict__ out,
                   int R, int C) {
  __shared__ float tile[64][65];
  int c0 = blockIdx.x * 64, r0 = blockIdx.y * 64;
  int tx = threadIdx.x & 63, ty = threadIdx.x >> 6;
  #pragma unroll
  for (int i = 0; i < 16; ++i) {
    int r = i * 4 + ty;
    tile[r][tx] = in[(size_t)(r0 + r) * C + c0 + tx];
  }
  __syncthreads();
  #pragma unroll
  for (int i = 0; i < 16; ++i) {
    int c = i * 4 + ty;
    out[(size_t)(c0 + c) * R + r0 + tx] = (_Float16)tile[tx][c];
  }
}

// ---------------- fp16 MFMA GEMM: C[M][N] = A[M][K] * Bt[N][K]^T ----------------
template <typename CT>
__global__ __launch_bounds__(256, 2)
void gemm_f16(const _Float16* __restrict__ A, const _Float16* __restrict__ Bt,
              CT* __restrict__ C, int M, int N, int K, int tiles_n) {
  __shared__ _Float16 lsA[128 * 32];
  __shared__ _Float16 lsB[128 * 32];
  int bm = blockIdx.x / tiles_n, bn = blockIdx.x % tiles_n;
  int m0 = bm * 128, n0 = bn * 128;
  int lane = threadIdx.x & 63, wid = threadIdx.x >> 6;
  int wr = wid >> 1, wc = wid & 1;
  int la = lane & 15, lk = lane >> 4;
  int ldrow = lane >> 2;          // 0..15
  int ldcol = (lane & 3) * 8;     // 8 halves = 16B
  f32x4 acc[4][4] = {};
  for (int k0 = 0; k0 < K; k0 += 32) {
    __syncthreads();
    #pragma unroll
    for (int si = 0; si < 2; ++si) {
      int seg = wid * 2 + si;               // 0..7, 16 rows each
      int row = seg * 16 + ldrow;
      gload_lds16(A  + (size_t)(m0 + row) * K + k0 + ldcol, &lsA[seg * 512]);
      gload_lds16(Bt + (size_t)(n0 + row) * K + k0 + ldcol, &lsB[seg * 512]);
    }
    __syncthreads();
    f16x8 af[4], bf[4];
    #pragma unroll
    for (int f = 0; f < 4; ++f) {
      af[f] = *(const f16x8*)&lsA[(wr * 64 + f * 16 + la) * 32 + lk * 8];
      bf[f] = *(const f16x8*)&lsB[(wc * 64 + f * 16 + la) * 32 + lk * 8];
    }
    #pragma unroll
    for (int i = 0; i < 4; ++i)
      #pragma unroll
      for (int j = 0; j < 4; ++j)
        acc[i][j] = __builtin_amdgcn_mfma_f32_16x16x32_f16(af[i], bf[j], acc[i][j], 0, 0, 0);
  }
  #pragma unroll
  for (int i = 0; i < 4; ++i)
    #pragma unroll
    for (int j = 0; j < 4; ++j) {
      int col = n0 + wc * 64 + j * 16 + la;
      #pragma unroll
      for (int r = 0; r < 4; ++r) {
        int row = m0 + wr * 64 + i * 16 + lk * 4 + r;
        C[(size_t)row * N + col] = (CT)acc[i][j][r];
      }
    }
}

// ---------------- ba = (h*mask) @ W_ba in fp32 (precision-critical for g) ----------------
__global__ __launch_bounds__(256)
void ba_gemm(const float* __restrict__ h, const float* __restrict__ mask,
             const float* __restrict__ Wba, float* __restrict__ ba) {
  __shared__ float red[4][8][64];
  int r0 = blockIdx.x * 8;
  int c = threadIdx.x & 63, kc = threadIdx.x >> 6;
  float acc[8] = {};
  const float* wp = Wba + (size_t)(kc * 512) * 64 + c;
  const float* hp = h + (size_t)r0 * HIDD + kc * 512;
  for (int i = 0; i < 512; ++i) {
    float w = wp[(size_t)i * 64];
    #pragma unroll
    for (int r = 0; r < 8; ++r)
      acc[r] += hp[(size_t)r * HIDD + i] * w;
  }
  #pragma unroll
  for (int r = 0; r < 8; ++r) red[kc][r][c] = acc[r];
  __syncthreads();
  if (kc == 0) {
    #pragma unroll
    for (int r = 0; r < 8; ++r) {
      float s = red[0][r][c] + red[1][r][c] + red[2][r][c] + red[3][r][c];
      ba[(size_t)(r0 + r) * 64 + c] = s * mask[r0 + r];
    }
  }
}

// ---------------- conv(4-tap causal) + SiLU + l2norm -> qn16, kn16, vb16 ----------------
__global__ __launch_bounds__(256)
void conv_kernel(const _Float16* __restrict__ qkvz, const float* __restrict__ ck,
                 _Float16* __restrict__ qn, _Float16* __restrict__ kn,
                 _Float16* __restrict__ vb) {
  int row = blockIdx.x;               // b*2048 + t
  int b = row >> 11, t = row & 2047;
  int lane = threadIdx.x & 63, wid = threadIdx.x >> 6;
  for (int u = wid; u < 64; u += 4) {
    int c, cc, hh;
    if (u < 16)      { hh = u;      c = hh * 768;                               cc = hh * 128; }
    else if (u < 32) { hh = u - 16; c = hh * 768 + 128;                         cc = 2048 + hh * 128; }
    else             { hh = u - 32; c = (hh >> 1) * 768 + 256 + (hh & 1) * 128; cc = 4096 + hh * 128; }
    float y0 = 0.f, y1 = 0.f;
    #pragma unroll
    for (int j = 0; j < 4; ++j) {
      int tt = t - 3 + j;
      if (tt >= 0) {
        const _Float16* r = qkvz + (size_t)(b * 2048 + tt) * NQKV + c;
        f16x2 x = *(const f16x2*)(r + 2 * lane);
        f32x2 w = *(const f32x2*)(ck + j * 8192 + cc + 2 * lane);
        y0 += (float)x[0] * w[0];
        y1 += (float)x[1] * w[1];
      }
    }
    y0 = y0 / (1.f + expf(-y0));
    y1 = y1 / (1.f + expf(-y1));
    if (u < 32) {
      float ss = y0 * y0 + y1 * y1;
      #pragma unroll
      for (int m = 1; m < 64; m <<= 1) ss += __shfl_xor(ss, m);
      float rs = rsqrtf(ss + 1e-6f);
      if (u < 16) rs *= 0.08838834764831845f;   // DK^-0.5
      y0 *= rs; y1 *= rs;
      _Float16* dst = (u < 16 ? qn : kn) + (size_t)row * 2048 + hh * 128;
      f16x2 o; o[0] = (_Float16)y0; o[1] = (_Float16)y1;
      *(f16x2*)(dst + 2 * lane) = o;
    } else {
      _Float16* dst = vb + (size_t)row * 4096 + hh * 128;
      f16x2 o; o[0] = (_Float16)y0; o[1] = (_Float16)y1;
      *(f16x2*)(dst + 2 * lane) = o;
    }
  }
}

// ---------------- g/beta from fp32 ba (interleaved e,b pairs for b64 LDS reads) ----------------
__global__ __launch_bounds__(256)
void egbeta_kernel(const float* __restrict__ ba, const float* __restrict__ Alog,
                   const float* __restrict__ dtb, float* __restrict__ eg,
                   float* __restrict__ bet) {
  int i = blockIdx.x * 256 + threadIdx.x;     // MROWS*32
  if (i >= MROWS * 32) return;
  int row = i >> 5, vh = i & 31;
  int kh = vh >> 1, r = vh & 1;
  const float* p = ba + (size_t)row * 64 + kh * 4;
  float bv = p[r], av = p[2 + r];
  float x = av + dtb[vh];
  float sp = (x > 20.f) ? x : log1pf(expf(x));
  eg[i]  = expf(-expf(Alog[vh]) * sp);
  bet[i] = 1.f / (1.f + expf(-bv));
}

// ---------------- gated delta-rule scan (o in-place into vb) ----------------
// 512 blocks x 256 thr (4 waves). block = (b, vh, vg: 16 v-cols).
// wave w: cols vg*16 + w*4 + vc, vc = lane>>4; kq = lane&15 owns k-slice [kq*8, +8).
// state s[8] fp32 in VGPRs. k/q/v staged fp16 in LDS via global_load_lds.
// Reduces over the 16 kq-lanes via DPP (VALU pipe) - zero DS shuffle ops.
__global__ __launch_bounds__(256, 2)
void scan_kernel(const _Float16* __restrict__ qn, const _Float16* __restrict__ kn,
                 _Float16* __restrict__ vb, const float* __restrict__ eg,
                 const float* __restrict__ bet) {
  __shared__ __align__(16) _Float16 kbuf[32 * 128];
  __shared__ __align__(16) _Float16 qbuf[32 * 128];
  __shared__ __align__(16) _Float16 vbuf[32 * 16];
  __shared__ __align__(16) float    ebbuf[64];      // interleaved e,b pairs: [2t]=e, [2t+1]=b
  int bid = blockIdx.x;
  int b = bid >> 8, vh = (bid >> 3) & 31, vg = bid & 7;
  int kh = vh >> 1;
  int tid = threadIdx.x;
  int w = tid >> 6, lane = tid & 63;
  int kq = lane & 15, vc = lane >> 4;
  int col = w * 4 + vc;                              // within block's 16 cols
  float s[8];
  #pragma unroll
  for (int i = 0; i < 8; ++i) s[i] = 0.f;
  const _Float16* kb  = kn + (size_t)b * SEQ * 2048 + kh * 128;
  const _Float16* qb  = qn + (size_t)b * SEQ * 2048 + kh * 128;
  _Float16*       vbm = vb + (size_t)b * SEQ * 4096 + vh * 128 + vg * 16;
  const float* ebase = eg  + (size_t)b * SEQ * 32 + vh;
  const float* bbase = bet + (size_t)b * SEQ * 32 + vh;
  int srow = lane >> 4, scol = (lane & 15) * 8;      // k/q staging: 4 rows per inst
  for (int t0 = 0; t0 < SEQ; t0 += 32) {
    // ---- stage chunk: k,q: 2 insts per wave; v: wave 2; e/b: wave 3 ----
    {
      int j0 = w * 2;
      gload_lds16(kb + (size_t)(t0 + j0 * 4 + srow) * 2048 + scol,       &kbuf[j0 * 512]);
      gload_lds16(kb + (size_t)(t0 + (j0 + 1) * 4 + srow) * 2048 + scol, &kbuf[(j0 + 1) * 512]);
      gload_lds16(qb + (size_t)(t0 + j0 * 4 + srow) * 2048 + scol,       &qbuf[j0 * 512]);
      gload_lds16(qb + (size_t)(t0 + (j0 + 1) * 4 + srow) * 2048 + scol, &qbuf[(j0 + 1) * 512]);
      if (w == 2)
        gload_lds16(vbm + (size_t)(t0 + (lane >> 1)) * 4096 + (lane & 1) * 8, vbuf);
      if (w == 3) {
        const float* src = (lane & 1) ? bbase + (size_t)(t0 + (lane >> 1)) * 32
                                      : ebase + (size_t)(t0 + (lane >> 1)) * 32;
        gload_lds4(src, ebbuf);
      }
    }
    __syncthreads();
    #pragma unroll 4
    for (int t = 0; t < 32; ++t) {
      f16x8 kf = *(const f16x8*)&kbuf[t * 128 + kq * 8];
      float p0 = 0.f, p1 = 0.f;
      #pragma unroll
      for (int i = 0; i < 4; ++i) {
        p0 += (float)kf[2 * i]     * s[2 * i];
        p1 += (float)kf[2 * i + 1] * s[2 * i + 1];
      }
      float p = rsum16(p0 + p1);
      f32x2 ebp = *(const f32x2*)&ebbuf[2 * t];
      float egt = ebp[0], btt = ebp[1];
      float vt = (float)vbuf[t * 16 + col];
      float delta = (vt - egt * p) * btt;            // kv uses decayed S
      f16x8 qf = *(const f16x8*)&qbuf[t * 128 + kq * 8];
      float o0 = 0.f, o1 = 0.f;
      #pragma unroll
      for (int i = 0; i < 4; ++i) {
        float u0 = (float)kf[2 * i] * delta;
        float u1 = (float)kf[2 * i + 1] * delta;
        s[2 * i]     = fmaf(s[2 * i],     egt, u0);
        s[2 * i + 1] = fmaf(s[2 * i + 1], egt, u1);
        o0 += (float)qf[2 * i]     * s[2 * i];
        o1 += (float)qf[2 * i + 1] * s[2 * i + 1];
      }
      float oo = rsum16(o0 + o1);
      if (kq == 0) vbm[(size_t)(t0 + t) * 4096 + col] = (_Float16)oo;   // in-place: v[t] dead
    }
    __syncthreads();
  }
}

// ---------------- RMSNorm * norm_kernel * silu(z) -> fp16 Ag ----------------
__global__ __launch_bounds__(256)
void gate_kernel(const _Float16* __restrict__ ob, const _Float16* __restrict__ qkvz,
                 const float* __restrict__ nk, _Float16* __restrict__ Ag) {
  int row = blockIdx.x;
  int lane = threadIdx.x & 63, wid = threadIdx.x >> 6;
  for (int vh = wid; vh < 32; vh += 4) {
    const _Float16* op = ob + (size_t)row * 4096 + vh * 128;
    f16x2 xx = *(const f16x2*)(op + 2 * lane);
    float x0 = (float)xx[0], x1 = (float)xx[1];
    float ss = x0 * x0 + x1 * x1;
    #pragma unroll
    for (int m = 1; m < 64; m <<= 1) ss += __shfl_xor(ss, m);
    float rs = rsqrtf(ss * (1.f / 128.f) + 1e-6f);
    f32x2 nv = *(const f32x2*)(nk + 2 * lane);
    float v0 = x0 * rs * nv[0], v1 = x1 * rs * nv[1];
    const _Float16* zp = qkvz + (size_t)row * NQKV + (vh >> 1) * 768 + 512 + (vh & 1) * 128;
    f16x2 zz = *(const f16x2*)(zp + 2 * lane);
    float z0 = (float)zz[0], z1 = (float)zz[1];
    v0 *= z0 / (1.f + expf(-z0));
    v1 *= z1 / (1.f + expf(-z1));
    _Float16* dst = Ag + (size_t)row * 4096 + vh * 128;
    f16x2 o; o[0] = (_Float16)v0; o[1] = (_Float16)v1;
    *(f16x2*)(dst + 2 * lane) = o;
  }
}

extern "C" void kernel_launch(void* const* d_in, const int* in_sizes, int n_in,
                              void* d_out, int out_size, void* d_ws, size_t ws_size,
                              hipStream_t stream) {
  const float* h     = (const float*)d_in[0];
  const float* mask  = (const float*)d_in[1];
  const float* Wqkvz = (const float*)d_in[2];
  const float* Wba   = (const float*)d_in[3];
  const float* ck    = (const float*)d_in[4];
  const float* Alog  = (const float*)d_in[5];
  const float* dtb   = (const float*)d_in[6];
  const float* nk    = (const float*)d_in[7];
  const float* Wout  = (const float*)d_in[8];
  float* out = (float*)d_out;

  char* w = (char*)d_ws;
  // arena layout (bytes); lifetimes allow heavy aliasing
  const size_t o_qkvz = 0;                         // 100,663,296  [gemm1 .. gate]
  const size_t o_A1   = 100663296;                 //  16,777,216  [amask .. gemm1]
  const size_t o_Bt1  = o_A1 + 16777216;           //  50,331,648  [transpose .. gemm1]
  const size_t o_ba   = o_Bt1 + 50331648;          //   1,048,576
  const size_t o_eg   = o_ba + 1048576;            //     524,288
  const size_t o_bt   = o_eg + 524288;             //     524,288
  const size_t total  = o_bt + 524288;             // 169,869,312 B = 162 MiB
  if (ws_size < total) return;

  _Float16* qkvz16 = (_Float16*)(w + o_qkvz);
  _Float16* A1     = (_Float16*)(w + o_A1);
  _Float16* Bt1    = (_Float16*)(w + o_Bt1);
  float*    ba32   = (float*)   (w + o_ba);
  float*    egb    = (float*)   (w + o_eg);
  float*    btb    = (float*)   (w + o_bt);
  // aliases over dead regions:
  _Float16* qn16 = (_Float16*)(w + o_A1);                    // over A1 (dead after gemm1)
  _Float16* kn16 = (_Float16*)(w + o_Bt1);                   // over Bt1[0:16M)
  _Float16* vb16 = (_Float16*)(w + o_Bt1 + 16777216);        // over Bt1[16M:50M); o in-place
  _Float16* Ag   = (_Float16*)(w + o_A1);                    // over qn+kn (dead after scan)
  _Float16* Wt2  = (_Float16*)(w + 0);                       // over qkvz (dead after gate)

  amask_kernel<<<MROWS * HIDD / 4 / 256, 256, 0, stream>>>(h, mask, A1);
  transpose_f16<<<dim3(192, 32), 256, 0, stream>>>(Wqkvz, Bt1, HIDD, NQKV);
  ba_gemm<<<MROWS / 8, 256, 0, stream>>>(h, mask, Wba, ba32);
  gemm_f16<_Float16><<<32 * 96, 256, 0, stream>>>(A1, Bt1, qkvz16, MROWS, NQKV, HIDD, 96);
  conv_kernel<<<MROWS, 256, 0, stream>>>(qkvz16, ck, qn16, kn16, vb16);
  egbeta_kernel<<<MROWS * 32 / 256, 256, 0, stream>>>(ba32, Alog, dtb, egb, btb);
  scan_kernel<<<512, 256, 0, stream>>>(qn16, kn16, vb16, egb, btb);
  gate_kernel<<<MROWS, 256, 0, stream>>>(vb16, qkvz16, nk, Ag);
  transpose_f16<<<dim3(32, 64), 256, 0, stream>>>(Wout, Wt2, 4096, HIDD);
  gemm_f16<float><<<32 * 16, 256, 0, stream>>>(Ag, Wt2, out, MROWS, HIDD, 4096, 16);
}

// Round 4
// 871.473 us; speedup vs baseline: 2.0809x; 1.2758x over previous
//
#include <hip/hip_runtime.h>
#include <stdint.h>

typedef float    f32x4 __attribute__((ext_vector_type(4)));
typedef float    f32x2 __attribute__((ext_vector_type(2)));
typedef _Float16 f16x8 __attribute__((ext_vector_type(8)));
typedef _Float16 f16x4 __attribute__((ext_vector_type(4)));
typedef _Float16 f16x2 __attribute__((ext_vector_type(2)));

#define SEQ   2048
#define HIDD  2048
#define MROWS 4096
#define NQKV  12288          // 96 tiles of 128, no pad
#define NCHUNK 32
#define CLEN   64

__device__ __forceinline__ void gload_lds16(const void* g, void* l) {
  __builtin_amdgcn_global_load_lds((const __attribute__((address_space(1))) uint32_t*)g,
                                   (__attribute__((address_space(3))) uint32_t*)l, 16, 0, 0);
}
// XOR swizzles (byte addressing) for bank-conflict-free f16 frag reads
__device__ __forceinline__ int swz256(int row, int colb) { return row * 256 + (colb ^ ((row & 7) << 4)); }
__device__ __forceinline__ int swz128(int row, int colb) { return row * 128 + (colb ^ ((row & 7) << 4)); }

// ---------------- A = (h * mask) -> fp16 ----------------
__global__ __launch_bounds__(256)
void amask_kernel(const float* __restrict__ h, const float* __restrict__ mask,
                  _Float16* __restrict__ A1) {
  int i = blockIdx.x * 256 + threadIdx.x;            // one float4 each
  if (i >= MROWS * HIDD / 4) return;
  f32x4 x = ((const f32x4*)h)[i];
  float m = mask[(i * 4) >> 11];
  f16x4 r;
  r[0] = (_Float16)(x[0] * m); r[1] = (_Float16)(x[1] * m);
  r[2] = (_Float16)(x[2] * m); r[3] = (_Float16)(x[3] * m);
  *(f16x4*)(A1 + (size_t)i * 4) = r;
}

// ---------------- transpose fp32 [R][C] -> fp16 [C][R] ----------------
__global__ __launch_bounds__(256)
void transpose_f16(const float* __restrict__ in, _Float16* __restrict__ out,
                   int R, int C) {
  __shared__ float tile[64][65];
  int c0 = blockIdx.x * 64, r0 = blockIdx.y * 64;
  int tx = threadIdx.x & 63, ty = threadIdx.x >> 6;
  #pragma unroll
  for (int i = 0; i < 16; ++i) {
    int r = i * 4 + ty;
    tile[r][tx] = in[(size_t)(r0 + r) * C + c0 + tx];
  }
  __syncthreads();
  #pragma unroll
  for (int i = 0; i < 16; ++i) {
    int c = i * 4 + ty;
    out[(size_t)(c0 + c) * R + r0 + tx] = (_Float16)tile[tx][c];
  }
}

// ---------------- fp16 MFMA GEMM: C[M][N] = A[M][K] * Bt[N][K]^T ----------------
template <typename CT>
__global__ __launch_bounds__(256, 2)
void gemm_f16(const _Float16* __restrict__ A, const _Float16* __restrict__ Bt,
              CT* __restrict__ C, int M, int N, int K, int tiles_n) {
  __shared__ _Float16 lsA[128 * 32];
  __shared__ _Float16 lsB[128 * 32];
  int bm = blockIdx.x / tiles_n, bn = blockIdx.x % tiles_n;
  int m0 = bm * 128, n0 = bn * 128;
  int lane = threadIdx.x & 63, wid = threadIdx.x >> 6;
  int wr = wid >> 1, wc = wid & 1;
  int la = lane & 15, lk = lane >> 4;
  int ldrow = lane >> 2;          // 0..15
  int ldcol = (lane & 3) * 8;     // 8 halves = 16B
  f32x4 acc[4][4] = {};
  for (int k0 = 0; k0 < K; k0 += 32) {
    __syncthreads();
    #pragma unroll
    for (int si = 0; si < 2; ++si) {
      int seg = wid * 2 + si;               // 0..7, 16 rows each
      int row = seg * 16 + ldrow;
      gload_lds16(A  + (size_t)(m0 + row) * K + k0 + ldcol, &lsA[seg * 512]);
      gload_lds16(Bt + (size_t)(n0 + row) * K + k0 + ldcol, &lsB[seg * 512]);
    }
    __syncthreads();
    f16x8 af[4], bf[4];
    #pragma unroll
    for (int f = 0; f < 4; ++f) {
      af[f] = *(const f16x8*)&lsA[(wr * 64 + f * 16 + la) * 32 + lk * 8];
      bf[f] = *(const f16x8*)&lsB[(wc * 64 + f * 16 + la) * 32 + lk * 8];
    }
    #pragma unroll
    for (int i = 0; i < 4; ++i)
      #pragma unroll
      for (int j = 0; j < 4; ++j)
        acc[i][j] = __builtin_amdgcn_mfma_f32_16x16x32_f16(af[i], bf[j], acc[i][j], 0, 0, 0);
  }
  #pragma unroll
  for (int i = 0; i < 4; ++i)
    #pragma unroll
    for (int j = 0; j < 4; ++j) {
      int col = n0 + wc * 64 + j * 16 + la;
      #pragma unroll
      for (int r = 0; r < 4; ++r) {
        int row = m0 + wr * 64 + i * 16 + lk * 4 + r;
        C[(size_t)row * N + col] = (CT)acc[i][j][r];
      }
    }
}

// ---------------- ba = (h*mask) @ W_ba in fp32 (precision-critical for g) ----------------
__global__ __launch_bounds__(256)
void ba_gemm(const float* __restrict__ h, const float* __restrict__ mask,
             const float* __restrict__ Wba, float* __restrict__ ba) {
  __shared__ float red[4][8][64];
  int r0 = blockIdx.x * 8;
  int c = threadIdx.x & 63, kc = threadIdx.x >> 6;
  float acc[8] = {};
  const float* wp = Wba + (size_t)(kc * 512) * 64 + c;
  const float* hp = h + (size_t)r0 * HIDD + kc * 512;
  for (int i = 0; i < 512; ++i) {
    float w = wp[(size_t)i * 64];
    #pragma unroll
    for (int r = 0; r < 8; ++r)
      acc[r] += hp[(size_t)r * HIDD + i] * w;
  }
  #pragma unroll
  for (int r = 0; r < 8; ++r) red[kc][r][c] = acc[r];
  __syncthreads();
  if (kc == 0) {
    #pragma unroll
    for (int r = 0; r < 8; ++r) {
      float s = red[0][r][c] + red[1][r][c] + red[2][r][c] + red[3][r][c];
      ba[(size_t)(r0 + r) * 64 + c] = s * mask[r0 + r];
    }
  }
}

// ---------------- conv(4-tap causal) + SiLU + l2norm -> qn16, kn16, vb16 ----------------
__global__ __launch_bounds__(256)
void conv_kernel(const _Float16* __restrict__ qkvz, const float* __restrict__ ck,
                 _Float16* __restrict__ qn, _Float16* __restrict__ kn,
                 _Float16* __restrict__ vb) {
  int row = blockIdx.x;               // b*2048 + t
  int b = row >> 11, t = row & 2047;
  int lane = threadIdx.x & 63, wid = threadIdx.x >> 6;
  for (int u = wid; u < 64; u += 4) {
    int c, cc, hh;
    if (u < 16)      { hh = u;      c = hh * 768;                               cc = hh * 128; }
    else if (u < 32) { hh = u - 16; c = hh * 768 + 128;                         cc = 2048 + hh * 128; }
    else             { hh = u - 32; c = (hh >> 1) * 768 + 256 + (hh & 1) * 128; cc = 4096 + hh * 128; }
    float y0 = 0.f, y1 = 0.f;
    #pragma unroll
    for (int j = 0; j < 4; ++j) {
      int tt = t - 3 + j;
      if (tt >= 0) {
        const _Float16* r = qkvz + (size_t)(b * 2048 + tt) * NQKV + c;
        f16x2 x = *(const f16x2*)(r + 2 * lane);
        f32x2 w = *(const f32x2*)(ck + j * 8192 + cc + 2 * lane);
        y0 += (float)x[0] * w[0];
        y1 += (float)x[1] * w[1];
      }
    }
    y0 = y0 / (1.f + expf(-y0));
    y1 = y1 / (1.f + expf(-y1));
    if (u < 32) {
      float ss = y0 * y0 + y1 * y1;
      #pragma unroll
      for (int m = 1; m < 64; m <<= 1) ss += __shfl_xor(ss, m);
      float rs = rsqrtf(ss + 1e-6f);
      if (u < 16) rs *= 0.08838834764831845f;   // DK^-0.5
      y0 *= rs; y1 *= rs;
      _Float16* dst = (u < 16 ? qn : kn) + (size_t)row * 2048 + hh * 128;
      f16x2 o; o[0] = (_Float16)y0; o[1] = (_Float16)y1;
      *(f16x2*)(dst + 2 * lane) = o;
    } else {
      _Float16* dst = vb + (size_t)row * 4096 + hh * 128;
      f16x2 o; o[0] = (_Float16)y0; o[1] = (_Float16)y1;
      *(f16x2*)(dst + 2 * lane) = o;
    }
  }
}

// ---------------- g/beta from fp32 ba; outputs TRANSPOSED [vh][b*2048+t] ----------------
// g is the RAW log-decay (not exponentiated): g = -exp(A_log)*softplus(alpha+dt_bias)
__global__ __launch_bounds__(256)
void egbeta_kernel(const float* __restrict__ ba, const float* __restrict__ Alog,
                   const float* __restrict__ dtb, float* __restrict__ gout,
                   float* __restrict__ bout) {
  int i = blockIdx.x * 256 + threadIdx.x;     // MROWS*32
  if (i >= MROWS * 32) return;
  int vh = i >> 12, row = i & 4095;
  int kh = vh >> 1, r = vh & 1;
  const float* p = ba + (size_t)row * 64 + kh * 4;
  float bv = p[r], av = p[2 + r];
  float x = av + dtb[vh];
  float sp = (x > 20.f) ? x : log1pf(expf(x));
  gout[(size_t)vh * MROWS + row] = -expf(Alog[vh]) * sp;
  bout[(size_t)vh * MROWS + row] = 1.f / (1.f + expf(-bv));
}

// ---------------- chunked gated delta-rule scan (UT transform, MFMA) ----------------
// block = (b, vh, vslice of 32 v-cols); 4 waves. chunk C=64, 32 serial chunks.
// Per chunk: A[t,s]=beta_s e^{cg_t-cg_s} k_t.k_s (strict lower);  (I+A)U = V - diag(b) K S0
// O = diag(b) Q S0 + tril_incl(M) U ;  S' = b_63 S0 + sum_s beta_s (b63/b_s) k_s^T u_s
__global__ __launch_bounds__(256, 1)
void chunk_scan(const _Float16* __restrict__ qn, const _Float16* __restrict__ kn,
                _Float16* __restrict__ vb, const float* __restrict__ gb,
                const float* __restrict__ btb) {
  __shared__ __align__(16) _Float16 Ks[64 * 128];   // [t][k] swz256
  __shared__ __align__(16) _Float16 Qs[64 * 128];   // [t][k] swz256
  __shared__ __align__(16) _Float16 Kt[128 * 64];   // [k][s] swz128
  __shared__ __align__(16) _Float16 Sf[32 * 128];   // [v][k] f16 copy of S, swz256
  __shared__ float S32[32 * 129];                   // [v][k] fp32 state
  __shared__ float AT[64 * 65];                     // AT[s][t] = A[t][s]
  __shared__ __align__(16) _Float16 M16[64 * 64];   // [t][s] swz128
  __shared__ float RHS[32 * 65];                    // [v][t]
  __shared__ __align__(16) _Float16 Uv[32 * 64];    // [v][s] swz128 (raw u)
  __shared__ __align__(16) _Float16 Ub[32 * 64];    // [v][s] swz128 (u * scU[s])
  __shared__ __align__(16) _Float16 Vb[64 * 32];    // [t][v] linear
  __shared__ float gs[64], bs[64], cgs[64], bexp[64], scU[64];

  char* Ksb = (char*)Ks; char* Qsb = (char*)Qs; char* Ktb = (char*)Kt;
  char* Sfb = (char*)Sf; char* M16b = (char*)M16;
  char* Uvb = (char*)Uv; char* Ubb = (char*)Ub; char* Vbb = (char*)Vb;

  int bid = blockIdx.x;
  int b = bid >> 7, vh = (bid >> 2) & 31, vsl = bid & 3;
  int kh = vh >> 1;
  int tid = threadIdx.x;
  int w = tid >> 6, lane = tid & 63;
  int la = lane & 15, lk = lane >> 4;

  const _Float16* kgb = kn + (size_t)(b * 2048) * 2048 + kh * 128;
  const _Float16* qgb = qn + (size_t)(b * 2048) * 2048 + kh * 128;
  _Float16*       vgb = vb + (size_t)(b * 2048) * 4096 + vh * 128 + vsl * 32;
  const float*    ggb = gb  + (size_t)vh * MROWS + b * 2048;
  const float*    bgb = btb + (size_t)vh * MROWS + b * 2048;

  // staging registers (chunk c+1)
  f16x8 kr[4], qr[4], vr;
  float ebr;
  int srow = lane, sq = w;             // K/Q: thread covers row srow, quarter sq (64B)
  int vrow = tid >> 2, vseg = tid & 3; // V: 16B per thread

  // zero state
  for (int i = tid; i < 32 * 129; i += 256) S32[i] = 0.f;
  for (int i = tid; i < 32 * 128; i += 256) Sf[i] = (_Float16)0;

  // stage chunk 0
  #pragma unroll
  for (int i = 0; i < 4; ++i) {
    kr[i] = *(const f16x8*)(kgb + (size_t)srow * 2048 + sq * 32 + i * 8);
    qr[i] = *(const f16x8*)(qgb + (size_t)srow * 2048 + sq * 32 + i * 8);
  }
  vr = *(const f16x8*)(vgb + (size_t)vrow * 4096 + vseg * 8);
  ebr = (tid < 64) ? ggb[tid] : (tid < 128 ? bgb[tid - 64] : 0.f);
  __syncthreads();
  #pragma unroll
  for (int i = 0; i < 4; ++i) {
    *(f16x8*)(Ksb + swz256(srow, sq * 64 + i * 16)) = kr[i];
    *(f16x8*)(Qsb + swz256(srow, sq * 64 + i * 16)) = qr[i];
  }
  *(f16x8*)(Vbb + vrow * 64 + vseg * 16) = vr;
  if (tid < 64) gs[tid] = ebr; else if (tid < 128) bs[tid - 64] = ebr;
  __syncthreads();

  #pragma unroll 1
  for (int c = 0; c < NCHUNK; ++c) {
    // ---- issue loads for next chunk (T14 early-issue) ----
    int cn = (c < NCHUNK - 1) ? c + 1 : c;
    #pragma unroll
    for (int i = 0; i < 4; ++i) {
      kr[i] = *(const f16x8*)(kgb + (size_t)(cn * 64 + srow) * 2048 + sq * 32 + i * 8);
      qr[i] = *(const f16x8*)(qgb + (size_t)(cn * 64 + srow) * 2048 + sq * 32 + i * 8);
    }
    vr = *(const f16x8*)(vgb + (size_t)(cn * 64 + vrow) * 4096 + vseg * 8);
    ebr = (tid < 64) ? ggb[cn * 64 + tid] : (tid < 128 ? bgb[cn * 64 + tid - 64] : 0.f);

    // ---- KK^T and QK^T (wave w owns t-rows [w*16, w*16+16)) ----
    f32x4 kk[4] = {}, qk[4] = {};
    #pragma unroll
    for (int ks = 0; ks < 4; ++ks) {
      f16x8 aK = *(const f16x8*)(Ksb + swz256(w * 16 + la, ks * 64 + lk * 16));
      f16x8 aQ = *(const f16x8*)(Qsb + swz256(w * 16 + la, ks * 64 + lk * 16));
      #pragma unroll
      for (int j = 0; j < 4; ++j) {
        f16x8 bK = *(const f16x8*)(Ksb + swz256(j * 16 + la, ks * 64 + lk * 16));
        kk[j] = __builtin_amdgcn_mfma_f32_16x16x32_f16(aK, bK, kk[j], 0, 0, 0);
        qk[j] = __builtin_amdgcn_mfma_f32_16x16x32_f16(aQ, bK, qk[j], 0, 0, 0);
      }
    }

    // ---- K transpose: Kt[k][t] (wave w does t in its row-block) ----
    {
      int t = w * 16 + la;
      #pragma unroll
      for (int i = 0; i < 4; ++i) {
        int o = lk + 4 * i;              // k-octet 0..15
        f16x8 kv = *(const f16x8*)(Ksb + swz256(t, o * 16));
        #pragma unroll
        for (int j = 0; j < 8; ++j)
          *(_Float16*)(Ktb + swz128(o * 8 + j, t * 2)) = kv[j];
      }
    }

    // ---- wave 0: cumulative decay + derived scales ----
    if (w == 0) {
      float g = gs[lane];
      #pragma unroll
      for (int off = 1; off < 64; off <<= 1) {
        float y = __shfl_up(g, off);
        if (lane >= off) g += y;
      }
      cgs[lane] = g;
      float cgL = __shfl(g, 63);
      bexp[lane] = expf(g);
      scU[lane] = bs[lane] * expf(cgL - g);
    }
    __syncthreads();   // B1

    // ---- build A (strict lower, transposed store) and M (incl lower, f16) ----
    {
      float cgt[4];
      #pragma unroll
      for (int r = 0; r < 4; ++r) cgt[r] = cgs[w * 16 + lk * 4 + r];
      #pragma unroll
      for (int j = 0; j < 4; ++j) {
        int s = j * 16 + la;
        float bsv = bs[s], cgss = cgs[s];
        #pragma unroll
        for (int r = 0; r < 4; ++r) {
          int t = w * 16 + lk * 4 + r;
          float e = bsv * expf(cgt[r] - cgss);
          AT[s * 65 + t] = (s < t) ? e * kk[j][r] : 0.f;
          float mm = (s <= t) ? e * qk[j][r] : 0.f;
          *(_Float16*)(M16b + swz128(t, s * 2)) = (_Float16)mm;
        }
      }
    }

    // ---- K S0 and Q S0 (S0 fp16 copy in Sf [v][k]) ----
    f32x4 ks0[2] = {}, qs0[2] = {};
    #pragma unroll
    for (int ks = 0; ks < 4; ++ks) {
      f16x8 aK = *(const f16x8*)(Ksb + swz256(w * 16 + la, ks * 64 + lk * 16));
      f16x8 aQ = *(const f16x8*)(Qsb + swz256(w * 16 + la, ks * 64 + lk * 16));
      #pragma unroll
      for (int vt = 0; vt < 2; ++vt) {
        f16x8 bS = *(const f16x8*)(Sfb + swz256(vt * 16 + la, ks * 64 + lk * 16));
        ks0[vt] = __builtin_amdgcn_mfma_f32_16x16x32_f16(aK, bS, ks0[vt], 0, 0, 0);
        qs0[vt] = __builtin_amdgcn_mfma_f32_16x16x32_f16(aQ, bS, qs0[vt], 0, 0, 0);
      }
    }
    // scale QS0 rows by b_t (kept in regs); RHS = V - b_t * (K S0)
    #pragma unroll
    for (int vt = 0; vt < 2; ++vt)
      #pragma unroll
      for (int r = 0; r < 4; ++r) {
        int t = w * 16 + lk * 4 + r;
        int v = vt * 16 + la;
        float be = bexp[t];
        qs0[vt][r] *= be;
        float vv = (float)*(const _Float16*)(Vbb + t * 64 + v * 2);
        RHS[v * 65 + t] = vv - be * ks0[vt][r];
      }
    __syncthreads();   // B2: AT, M16, Kt, RHS ready

    // ---- forward substitution: lane = t; wave handles v-rows [w*8, w*8+8) ----
    float u[8];
    #pragma unroll
    for (int vi = 0; vi < 8; ++vi) u[vi] = RHS[(w * 8 + vi) * 65 + lane];
    #pragma unroll 1
    for (int sb = 0; sb < 8; ++sb) {
      float Ac[8];
      #pragma unroll
      for (int j = 0; j < 8; ++j) Ac[j] = AT[(sb * 8 + j) * 65 + lane];
      #pragma unroll
      for (int j = 0; j < 8; ++j) {
        int s = sb * 8 + j;
        #pragma unroll
        for (int vi = 0; vi < 8; ++vi) {
          float ubv = __builtin_bit_cast(float,
              __builtin_amdgcn_readlane(__builtin_bit_cast(int, u[vi]), s));
          u[vi] = fmaf(-Ac[j], ubv, u[vi]);
        }
      }
    }
    {
      float sc = scU[lane];
      #pragma unroll
      for (int vi = 0; vi < 8; ++vi) {
        int v = w * 8 + vi;
        *(_Float16*)(Uvb + swz128(v, lane * 2)) = (_Float16)u[vi];
        *(_Float16*)(Ubb + swz128(v, lane * 2)) = (_Float16)(u[vi] * sc);
      }
    }
    __syncthreads();   // B3: U ready

    // ---- O = (b.QS0) + M U ; store to global (in-place over v) ----
    #pragma unroll
    for (int ss = 0; ss < 2; ++ss) {
      f16x8 aM = *(const f16x8*)(M16b + swz128(w * 16 + la, ss * 64 + lk * 16));
      #pragma unroll
      for (int vt = 0; vt < 2; ++vt) {
        f16x8 bU = *(const f16x8*)(Uvb + swz128(vt * 16 + la, ss * 64 + lk * 16));
        qs0[vt] = __builtin_amdgcn_mfma_f32_16x16x32_f16(aM, bU, qs0[vt], 0, 0, 0);
      }
    }
    #pragma unroll
    for (int vt = 0; vt < 2; ++vt)
      #pragma unroll
      for (int r = 0; r < 4; ++r) {
        int t = w * 16 + lk * 4 + r;
        vgb[(size_t)(c * 64 + t) * 4096 + vt * 16 + la] = (_Float16)qs0[vt][r];
      }

    // ---- S update: Sdelta[v][k] = sum_s Ub[v][s] Kt[k][s]; S = b63*S + Sdelta ----
    f32x4 sd[2][2] = {};
    #pragma unroll
    for (int ss = 0; ss < 2; ++ss) {
      f16x8 aU0 = *(const f16x8*)(Ubb + swz128(la, ss * 64 + lk * 16));
      f16x8 aU1 = *(const f16x8*)(Ubb + swz128(16 + la, ss * 64 + lk * 16));
      #pragma unroll
      for (int kt = 0; kt < 2; ++kt) {
        f16x8 bK = *(const f16x8*)(Ktb + swz128((w * 2 + kt) * 16 + la, ss * 64 + lk * 16));
        sd[kt][0] = __builtin_amdgcn_mfma_f32_16x16x32_f16(aU0, bK, sd[kt][0], 0, 0, 0);
        sd[kt][1] = __builtin_amdgcn_mfma_f32_16x16x32_f16(aU1, bK, sd[kt][1], 0, 0, 0);
      }
    }
    {
      float beC = bexp[63];
      #pragma unroll
      for (int kt = 0; kt < 2; ++kt)
        #pragma unroll
        for (int vt = 0; vt < 2; ++vt)
          #pragma unroll
          for (int r = 0; r < 4; ++r) {
            int v = vt * 16 + lk * 4 + r;
            int k = (w * 2 + kt) * 16 + la;
            float sn = fmaf(S32[v * 129 + k], beC, sd[kt][vt][r]);
            S32[v * 129 + k] = sn;
            *(_Float16*)(Sfb + swz256(v, k * 2)) = (_Float16)sn;
          }
    }
    __syncthreads();   // B4: all reads of Ks/Qs/Vb/gs/bs done; Sf written

    // ---- write staged chunk c+1 (T14 write-late) ----
    #pragma unroll
    for (int i = 0; i < 4; ++i) {
      *(f16x8*)(Ksb + swz256(srow, sq * 64 + i * 16)) = kr[i];
      *(f16x8*)(Qsb + swz256(srow, sq * 64 + i * 16)) = qr[i];
    }
    *(f16x8*)(Vbb + vrow * 64 + vseg * 16) = vr;
    if (tid < 64) gs[tid] = ebr; else if (tid < 128) bs[tid - 64] = ebr;
    __syncthreads();   // B5
  }
}

// ---------------- RMSNorm * norm_kernel * silu(z) -> fp16 Ag ----------------
__global__ __launch_bounds__(256)
void gate_kernel(const _Float16* __restrict__ ob, const _Float16* __restrict__ qkvz,
                 const float* __restrict__ nk, _Float16* __restrict__ Ag) {
  int row = blockIdx.x;
  int lane = threadIdx.x & 63, wid = threadIdx.x >> 6;
  for (int vh = wid; vh < 32; vh += 4) {
    const _Float16* op = ob + (size_t)row * 4096 + vh * 128;
    f16x2 xx = *(const f16x2*)(op + 2 * lane);
    float x0 = (float)xx[0], x1 = (float)xx[1];
    float ss = x0 * x0 + x1 * x1;
    #pragma unroll
    for (int m = 1; m < 64; m <<= 1) ss += __shfl_xor(ss, m);
    float rs = rsqrtf(ss * (1.f / 128.f) + 1e-6f);
    f32x2 nv = *(const f32x2*)(nk + 2 * lane);
    float v0 = x0 * rs * nv[0], v1 = x1 * rs * nv[1];
    const _Float16* zp = qkvz + (size_t)row * NQKV + (vh >> 1) * 768 + 512 + (vh & 1) * 128;
    f16x2 zz = *(const f16x2*)(zp + 2 * lane);
    float z0 = (float)zz[0], z1 = (float)zz[1];
    v0 *= z0 / (1.f + expf(-z0));
    v1 *= z1 / (1.f + expf(-z1));
    _Float16* dst = Ag + (size_t)row * 4096 + vh * 128;
    f16x2 o; o[0] = (_Float16)v0; o[1] = (_Float16)v1;
    *(f16x2*)(dst + 2 * lane) = o;
  }
}

extern "C" void kernel_launch(void* const* d_in, const int* in_sizes, int n_in,
                              void* d_out, int out_size, void* d_ws, size_t ws_size,
                              hipStream_t stream) {
  const float* h     = (const float*)d_in[0];
  const float* mask  = (const float*)d_in[1];
  const float* Wqkvz = (const float*)d_in[2];
  const float* Wba   = (const float*)d_in[3];
  const float* ck    = (const float*)d_in[4];
  const float* Alog  = (const float*)d_in[5];
  const float* dtb   = (const float*)d_in[6];
  const float* nk    = (const float*)d_in[7];
  const float* Wout  = (const float*)d_in[8];
  float* out = (float*)d_out;

  char* w = (char*)d_ws;
  const size_t o_qkvz = 0;                         // 100,663,296  [gemm1 .. gate]
  const size_t o_A1   = 100663296;                 //  16,777,216  [amask .. gemm1]
  const size_t o_Bt1  = o_A1 + 16777216;           //  50,331,648  [transpose .. gemm1]
  const size_t o_ba   = o_Bt1 + 50331648;          //   1,048,576
  const size_t o_g    = o_ba + 1048576;            //     524,288
  const size_t o_bt   = o_g + 524288;              //     524,288
  const size_t total  = o_bt + 524288;             // 169,869,312 B = 162 MiB
  if (ws_size < total) return;

  _Float16* qkvz16 = (_Float16*)(w + o_qkvz);
  _Float16* A1     = (_Float16*)(w + o_A1);
  _Float16* Bt1    = (_Float16*)(w + o_Bt1);
  float*    ba32   = (float*)   (w + o_ba);
  float*    gbuf   = (float*)   (w + o_g);
  float*    btb    = (float*)   (w + o_bt);
  // aliases over dead regions:
  _Float16* qn16 = (_Float16*)(w + o_A1);                    // over A1 (dead after gemm1)
  _Float16* kn16 = (_Float16*)(w + o_Bt1);                   // over Bt1[0:16M)
  _Float16* vb16 = (_Float16*)(w + o_Bt1 + 16777216);        // over Bt1[16M:50M); o in-place
  _Float16* Ag   = (_Float16*)(w + o_A1);                    // over qn+kn (dead after scan)
  _Float16* Wt2  = (_Float16*)(w + 0);                       // over qkvz (dead after gate)

  amask_kernel<<<MROWS * HIDD / 4 / 256, 256, 0, stream>>>(h, mask, A1);
  transpose_f16<<<dim3(192, 32), 256, 0, stream>>>(Wqkvz, Bt1, HIDD, NQKV);
  ba_gemm<<<MROWS / 8, 256, 0, stream>>>(h, mask, Wba, ba32);
  gemm_f16<_Float16><<<32 * 96, 256, 0, stream>>>(A1, Bt1, qkvz16, MROWS, NQKV, HIDD, 96);
  conv_kernel<<<MROWS, 256, 0, stream>>>(qkvz16, ck, qn16, kn16, vb16);
  egbeta_kernel<<<MROWS * 32 / 256, 256, 0, stream>>>(ba32, Alog, dtb, gbuf, btb);
  chunk_scan<<<256, 256, 0, stream>>>(qn16, kn16, vb16, gbuf, btb);
  gate_kernel<<<MROWS, 256, 0, stream>>>(vb16, qkvz16, nk, Ag);
  transpose_f16<<<dim3(32, 64), 256, 0, stream>>>(Wout, Wt2, 4096, HIDD);
  gemm_f16<float><<<32 * 16, 256, 0, stream>>>(Ag, Wt2, out, MROWS, HIDD, 4096, 16);
}

// Round 5
// 782.922 us; speedup vs baseline: 2.3162x; 1.1131x over previous
//
#include <hip/hip_runtime.h>
#include <stdint.h>

typedef float    f32x4 __attribute__((ext_vector_type(4)));
typedef float    f32x2 __attribute__((ext_vector_type(2)));
typedef _Float16 f16x8 __attribute__((ext_vector_type(8)));
typedef _Float16 f16x4 __attribute__((ext_vector_type(4)));
typedef _Float16 f16x2 __attribute__((ext_vector_type(2)));

#define SEQ   2048
#define HIDD  2048
#define MROWS 4096
#define NQKV  12288          // 96 tiles of 128, no pad
#define NCHUNK 32
#define CLEN   64

__device__ __forceinline__ void gload_lds16(const void* g, void* l) {
  __builtin_amdgcn_global_load_lds((const __attribute__((address_space(1))) uint32_t*)g,
                                   (__attribute__((address_space(3))) uint32_t*)l, 16, 0, 0);
}
// XOR swizzles (byte addressing) for bank-conflict-free f16 frag reads
__device__ __forceinline__ int swz256(int row, int colb) { return row * 256 + (colb ^ ((row & 7) << 4)); }
__device__ __forceinline__ int swz128(int row, int colb) { return row * 128 + (colb ^ ((row & 7) << 4)); }

// ---------------- A = (h * mask) -> fp16 ----------------
__global__ __launch_bounds__(256)
void amask_kernel(const float* __restrict__ h, const float* __restrict__ mask,
                  _Float16* __restrict__ A1) {
  int i = blockIdx.x * 256 + threadIdx.x;            // one float4 each
  if (i >= MROWS * HIDD / 4) return;
  f32x4 x = ((const f32x4*)h)[i];
  float m = mask[(i * 4) >> 11];
  f16x4 r;
  r[0] = (_Float16)(x[0] * m); r[1] = (_Float16)(x[1] * m);
  r[2] = (_Float16)(x[2] * m); r[3] = (_Float16)(x[3] * m);
  *(f16x4*)(A1 + (size_t)i * 4) = r;
}

// ---------------- transpose fp32 [R][C] -> fp16 [C][R] ----------------
__global__ __launch_bounds__(256)
void transpose_f16(const float* __restrict__ in, _Float16* __restrict__ out,
                   int R, int C) {
  __shared__ float tile[64][65];
  int c0 = blockIdx.x * 64, r0 = blockIdx.y * 64;
  int tx = threadIdx.x & 63, ty = threadIdx.x >> 6;
  #pragma unroll
  for (int i = 0; i < 16; ++i) {
    int r = i * 4 + ty;
    tile[r][tx] = in[(size_t)(r0 + r) * C + c0 + tx];
  }
  __syncthreads();
  #pragma unroll
  for (int i = 0; i < 16; ++i) {
    int c = i * 4 + ty;
    out[(size_t)(c0 + c) * R + r0 + tx] = (_Float16)tile[tx][c];
  }
}

// ---------------- fp16 MFMA GEMM: C[M][N] = A[M][K] * Bt[N][K]^T ----------------
template <typename CT>
__global__ __launch_bounds__(256, 2)
void gemm_f16(const _Float16* __restrict__ A, const _Float16* __restrict__ Bt,
              CT* __restrict__ C, int M, int N, int K, int tiles_n) {
  __shared__ _Float16 lsA[128 * 32];
  __shared__ _Float16 lsB[128 * 32];
  int bm = blockIdx.x / tiles_n, bn = blockIdx.x % tiles_n;
  int m0 = bm * 128, n0 = bn * 128;
  int lane = threadIdx.x & 63, wid = threadIdx.x >> 6;
  int wr = wid >> 1, wc = wid & 1;
  int la = lane & 15, lk = lane >> 4;
  int ldrow = lane >> 2;          // 0..15
  int ldcol = (lane & 3) * 8;     // 8 halves = 16B
  f32x4 acc[4][4] = {};
  for (int k0 = 0; k0 < K; k0 += 32) {
    __syncthreads();
    #pragma unroll
    for (int si = 0; si < 2; ++si) {
      int seg = wid * 2 + si;               // 0..7, 16 rows each
      int row = seg * 16 + ldrow;
      gload_lds16(A  + (size_t)(m0 + row) * K + k0 + ldcol, &lsA[seg * 512]);
      gload_lds16(Bt + (size_t)(n0 + row) * K + k0 + ldcol, &lsB[seg * 512]);
    }
    __syncthreads();
    f16x8 af[4], bf[4];
    #pragma unroll
    for (int f = 0; f < 4; ++f) {
      af[f] = *(const f16x8*)&lsA[(wr * 64 + f * 16 + la) * 32 + lk * 8];
      bf[f] = *(const f16x8*)&lsB[(wc * 64 + f * 16 + la) * 32 + lk * 8];
    }
    #pragma unroll
    for (int i = 0; i < 4; ++i)
      #pragma unroll
      for (int j = 0; j < 4; ++j)
        acc[i][j] = __builtin_amdgcn_mfma_f32_16x16x32_f16(af[i], bf[j], acc[i][j], 0, 0, 0);
  }
  #pragma unroll
  for (int i = 0; i < 4; ++i)
    #pragma unroll
    for (int j = 0; j < 4; ++j) {
      int col = n0 + wc * 64 + j * 16 + la;
      #pragma unroll
      for (int r = 0; r < 4; ++r) {
        int row = m0 + wr * 64 + i * 16 + lk * 4 + r;
        C[(size_t)row * N + col] = (CT)acc[i][j][r];
      }
    }
}

// ---------------- ba = (h*mask) @ W_ba in fp32 (precision-critical for g) ----------------
__global__ __launch_bounds__(256)
void ba_gemm(const float* __restrict__ h, const float* __restrict__ mask,
             const float* __restrict__ Wba, float* __restrict__ ba) {
  __shared__ float red[4][8][64];
  int r0 = blockIdx.x * 8;
  int c = threadIdx.x & 63, kc = threadIdx.x >> 6;
  float acc[8] = {};
  const float* wp = Wba + (size_t)(kc * 512) * 64 + c;
  const float* hp = h + (size_t)r0 * HIDD + kc * 512;
  for (int i = 0; i < 512; ++i) {
    float w = wp[(size_t)i * 64];
    #pragma unroll
    for (int r = 0; r < 8; ++r)
      acc[r] += hp[(size_t)r * HIDD + i] * w;
  }
  #pragma unroll
  for (int r = 0; r < 8; ++r) red[kc][r][c] = acc[r];
  __syncthreads();
  if (kc == 0) {
    #pragma unroll
    for (int r = 0; r < 8; ++r) {
      float s = red[0][r][c] + red[1][r][c] + red[2][r][c] + red[3][r][c];
      ba[(size_t)(r0 + r) * 64 + c] = s * mask[r0 + r];
    }
  }
}

// ---------------- conv(4-tap causal) + SiLU + l2norm -> qn16, kn16, vb16 ----------------
__global__ __launch_bounds__(256)
void conv_kernel(const _Float16* __restrict__ qkvz, const float* __restrict__ ck,
                 _Float16* __restrict__ qn, _Float16* __restrict__ kn,
                 _Float16* __restrict__ vb) {
  int row = blockIdx.x;               // b*2048 + t
  int b = row >> 11, t = row & 2047;
  int lane = threadIdx.x & 63, wid = threadIdx.x >> 6;
  for (int u = wid; u < 64; u += 4) {
    int c, cc, hh;
    if (u < 16)      { hh = u;      c = hh * 768;                               cc = hh * 128; }
    else if (u < 32) { hh = u - 16; c = hh * 768 + 128;                         cc = 2048 + hh * 128; }
    else             { hh = u - 32; c = (hh >> 1) * 768 + 256 + (hh & 1) * 128; cc = 4096 + hh * 128; }
    float y0 = 0.f, y1 = 0.f;
    #pragma unroll
    for (int j = 0; j < 4; ++j) {
      int tt = t - 3 + j;
      if (tt >= 0) {
        const _Float16* r = qkvz + (size_t)(b * 2048 + tt) * NQKV + c;
        f16x2 x = *(const f16x2*)(r + 2 * lane);
        f32x2 w = *(const f32x2*)(ck + j * 8192 + cc + 2 * lane);
        y0 += (float)x[0] * w[0];
        y1 += (float)x[1] * w[1];
      }
    }
    y0 = y0 / (1.f + expf(-y0));
    y1 = y1 / (1.f + expf(-y1));
    if (u < 32) {
      float ss = y0 * y0 + y1 * y1;
      #pragma unroll
      for (int m = 1; m < 64; m <<= 1) ss += __shfl_xor(ss, m);
      float rs = rsqrtf(ss + 1e-6f);
      if (u < 16) rs *= 0.08838834764831845f;   // DK^-0.5
      y0 *= rs; y1 *= rs;
      _Float16* dst = (u < 16 ? qn : kn) + (size_t)row * 2048 + hh * 128;
      f16x2 o; o[0] = (_Float16)y0; o[1] = (_Float16)y1;
      *(f16x2*)(dst + 2 * lane) = o;
    } else {
      _Float16* dst = vb + (size_t)row * 4096 + hh * 128;
      f16x2 o; o[0] = (_Float16)y0; o[1] = (_Float16)y1;
      *(f16x2*)(dst + 2 * lane) = o;
    }
  }
}

// ---------------- g/beta from fp32 ba; outputs TRANSPOSED [vh][b*2048+t] ----------------
// g is the RAW log-decay (not exponentiated): g = -exp(A_log)*softplus(alpha+dt_bias)
__global__ __launch_bounds__(256)
void egbeta_kernel(const float* __restrict__ ba, const float* __restrict__ Alog,
                   const float* __restrict__ dtb, float* __restrict__ gout,
                   float* __restrict__ bout) {
  int i = blockIdx.x * 256 + threadIdx.x;     // MROWS*32
  if (i >= MROWS * 32) return;
  int vh = i >> 12, row = i & 4095;
  int kh = vh >> 1, r = vh & 1;
  const float* p = ba + (size_t)row * 64 + kh * 4;
  float bv = p[r], av = p[2 + r];
  float x = av + dtb[vh];
  float sp = (x > 20.f) ? x : log1pf(expf(x));
  gout[(size_t)vh * MROWS + row] = -expf(Alog[vh]) * sp;
  bout[(size_t)vh * MROWS + row] = 1.f / (1.f + expf(-bv));
}

// ---------------- chunked gated delta-rule scan (UT transform, MFMA, 8 waves) ----------------
// block = (b, vh, vslice of 32 v-cols); 512 thr = 8 waves -> 2 waves/SIMD.
// wave w: wr = w>>1 (t-row block of 16), wc = w&1 (s/v half or v-16-col tile).
// Per chunk c: A[t,s]=beta_s e^{cg_t-cg_s} k_t.k_s (strict lower); (I+A)U = V - diag(b) K S0
// O = diag(b) Q S0 + tril_incl(M) U ;  S' = b63 S0 + sum_s beta_s (b63/b_s) k_s^T u_s
// State S held in REGISTERS (8 fp32/thread, MFMA fragment layout) + f16 copy in LDS (Sf).
__global__ __launch_bounds__(512, 2)
void chunk_scan(const _Float16* __restrict__ qn, const _Float16* __restrict__ kn,
                _Float16* __restrict__ vb, const float* __restrict__ gb,
                const float* __restrict__ btb) {
  __shared__ __align__(16) _Float16 Ks[64 * 128];   // [t][k] swz256
  __shared__ __align__(16) _Float16 Qs[64 * 128];   // [t][k] swz256
  __shared__ __align__(16) _Float16 Kt[128 * 64];   // [k][s] swz128
  __shared__ __align__(16) _Float16 Sf[32 * 128];   // [v][k] f16 state copy, swz256
  __shared__ float AT[64 * 65];                     // AT[s][t] = A[t][s]
  __shared__ __align__(16) _Float16 M16[64 * 64];   // [t][s] swz128
  __shared__ float RHS[32 * 65];                    // [v][t]
  __shared__ __align__(16) _Float16 Uv[32 * 64];    // [v][s] swz128 (raw u)
  __shared__ __align__(16) _Float16 Ub[32 * 64];    // [v][s] swz128 (u * scU[s])
  __shared__ __align__(16) _Float16 Vb[64 * 32];    // [t][v] linear, 64B rows
  __shared__ float gs[64], bs[64], cgs[64], bexp[64], scU[64];

  char* Ksb = (char*)Ks; char* Qsb = (char*)Qs; char* Ktb = (char*)Kt;
  char* Sfb = (char*)Sf; char* M16b = (char*)M16;
  char* Uvb = (char*)Uv; char* Ubb = (char*)Ub; char* Vbb = (char*)Vb;

  int bid = blockIdx.x;
  int b = bid >> 7, vh = (bid >> 2) & 31, vsl = bid & 3;
  int kh = vh >> 1;
  int tid = threadIdx.x;
  int w = tid >> 6, lane = tid & 63;
  int wr = w >> 1, wc = w & 1;
  int la = lane & 15, lk = lane >> 4;

  const _Float16* kgb = kn + (size_t)(b * 2048) * 2048 + kh * 128;
  const _Float16* qgb = qn + (size_t)(b * 2048) * 2048 + kh * 128;
  _Float16*       vgb = vb + (size_t)(b * 2048) * 4096 + vh * 128 + vsl * 32;
  const float*    ggb = gb  + (size_t)vh * MROWS + b * 2048;
  const float*    bgb = btb + (size_t)vh * MROWS + b * 2048;

  // staging: K/Q: thread covers (row = tid>>3, 32B seg = tid&7); V: 8B per thread
  int srow = tid >> 3, sseg = tid & 7;
  // transpose: thread = (k-row tk, t-quarter tth)
  int tk = tid & 127, tth = tid >> 7;

  f16x8 kr[2], qr[2]; f16x4 vr; float ebr;
  float sreg[2][4] = {};                 // S[v = vt*16+lk*4+r][k = w*16+la]

  // zero Sf: 8192 B = 512 threads x 16B
  { f32x4 z = {}; ((f32x4*)Sf)[tid] = z; }

  // stage chunk 0
  kr[0] = *(const f16x8*)(kgb + (size_t)srow * 2048 + sseg * 16);
  kr[1] = *(const f16x8*)(kgb + (size_t)srow * 2048 + sseg * 16 + 8);
  qr[0] = *(const f16x8*)(qgb + (size_t)srow * 2048 + sseg * 16);
  qr[1] = *(const f16x8*)(qgb + (size_t)srow * 2048 + sseg * 16 + 8);
  vr    = *(const f16x4*)(vgb + (size_t)srow * 4096 + sseg * 4);
  ebr   = (tid < 64) ? ggb[tid] : (tid < 128 ? bgb[tid - 64] : 0.f);
  *(f16x8*)(Ksb + swz256(srow, sseg * 32))      = kr[0];
  *(f16x8*)(Ksb + swz256(srow, sseg * 32 + 16)) = kr[1];
  *(f16x8*)(Qsb + swz256(srow, sseg * 32))      = qr[0];
  *(f16x8*)(Qsb + swz256(srow, sseg * 32 + 16)) = qr[1];
  *(f16x4*)(Vbb + srow * 64 + sseg * 8) = vr;
  if (tid < 64) gs[tid] = ebr; else if (tid < 128) bs[tid - 64] = ebr;
  __syncthreads();

  #pragma unroll 1
  for (int c = 0; c < NCHUNK; ++c) {
    // ---- P1: issue next-chunk loads; KK/QK + KS0/QS0 MFMA; Kt transpose; cumsum ----
    int cn = (c < NCHUNK - 1) ? c + 1 : c;
    kr[0] = *(const f16x8*)(kgb + (size_t)(cn * 64 + srow) * 2048 + sseg * 16);
    kr[1] = *(const f16x8*)(kgb + (size_t)(cn * 64 + srow) * 2048 + sseg * 16 + 8);
    qr[0] = *(const f16x8*)(qgb + (size_t)(cn * 64 + srow) * 2048 + sseg * 16);
    qr[1] = *(const f16x8*)(qgb + (size_t)(cn * 64 + srow) * 2048 + sseg * 16 + 8);
    vr    = *(const f16x4*)(vgb + (size_t)(cn * 64 + srow) * 4096 + sseg * 4);
    ebr   = (tid < 64) ? ggb[cn * 64 + tid] : (tid < 128 ? bgb[cn * 64 + tid - 64] : 0.f);

    f32x4 kk[2] = {}, qk[2] = {}, ks0 = {}, qs0 = {};
    #pragma unroll
    for (int ks = 0; ks < 4; ++ks) {
      f16x8 aK = *(const f16x8*)(Ksb + swz256(wr * 16 + la, ks * 64 + lk * 16));
      f16x8 aQ = *(const f16x8*)(Qsb + swz256(wr * 16 + la, ks * 64 + lk * 16));
      f16x8 bS = *(const f16x8*)(Sfb + swz256(wc * 16 + la, ks * 64 + lk * 16));
      #pragma unroll
      for (int j = 0; j < 2; ++j) {
        f16x8 bK = *(const f16x8*)(Ksb + swz256(wc * 32 + j * 16 + la, ks * 64 + lk * 16));
        kk[j] = __builtin_amdgcn_mfma_f32_16x16x32_f16(aK, bK, kk[j], 0, 0, 0);
        qk[j] = __builtin_amdgcn_mfma_f32_16x16x32_f16(aQ, bK, qk[j], 0, 0, 0);
      }
      ks0 = __builtin_amdgcn_mfma_f32_16x16x32_f16(aK, bS, ks0, 0, 0, 0);
      qs0 = __builtin_amdgcn_mfma_f32_16x16x32_f16(aQ, bS, qs0, 0, 0, 0);
    }
    // Kt transpose: column reads (conflict-free) + b128 row writes
    {
      f16x8 r0, r1;
      #pragma unroll
      for (int j = 0; j < 8; ++j) {
        r0[j] = *(const _Float16*)(Ksb + swz256(tth * 16 + j, 2 * tk));
        r1[j] = *(const _Float16*)(Ksb + swz256(tth * 16 + 8 + j, 2 * tk));
      }
      *(f16x8*)(Ktb + swz128(tk, tth * 32))      = r0;
      *(f16x8*)(Ktb + swz128(tk, tth * 32 + 16)) = r1;
    }
    if (w == 0) {
      float g = gs[lane];
      #pragma unroll
      for (int off = 1; off < 64; off <<= 1) {
        float y = __shfl_up(g, off);
        if (lane >= off) g += y;
      }
      cgs[lane] = g;
      float cgL = __shfl(g, 63);
      bexp[lane] = __expf(g);
      scU[lane] = bs[lane] * __expf(cgL - g);
    }
    __syncthreads();   // B1

    // ---- P2: build A (strict lower, transposed) and M (incl lower, f16); RHS ----
    {
      float cgt[4];
      #pragma unroll
      for (int r = 0; r < 4; ++r) cgt[r] = cgs[wr * 16 + lk * 4 + r];
      #pragma unroll
      for (int j = 0; j < 2; ++j) {
        int s = wc * 32 + j * 16 + la;
        float bsv = bs[s], cgss = cgs[s];
        #pragma unroll
        for (int r = 0; r < 4; ++r) {
          int t = wr * 16 + lk * 4 + r;
          float e = bsv * __expf(cgt[r] - cgss);
          AT[s * 65 + t] = (s < t) ? e * kk[j][r] : 0.f;
          float mm = (s <= t) ? e * qk[j][r] : 0.f;
          *(_Float16*)(M16b + swz128(t, s * 2)) = (_Float16)mm;
        }
      }
      #pragma unroll
      for (int r = 0; r < 4; ++r) {
        int t = wr * 16 + lk * 4 + r;
        int v = wc * 16 + la;
        float be = bexp[t];
        qs0[r] *= be;
        float vv = (float)*(const _Float16*)(Vbb + t * 64 + v * 2);
        RHS[v * 65 + t] = vv - be * ks0[r];
      }
    }
    __syncthreads();   // B2

    // ---- P3: forward substitution (lane = t; wave owns v-rows w*4..w*4+3) ----
    {
      float u[4];
      #pragma unroll
      for (int vi = 0; vi < 4; ++vi) u[vi] = RHS[(w * 4 + vi) * 65 + lane];
      #pragma unroll 1
      for (int sb = 0; sb < 8; ++sb) {
        float Ac[8];
        #pragma unroll
        for (int j = 0; j < 8; ++j) Ac[j] = AT[(sb * 8 + j) * 65 + lane];
        #pragma unroll
        for (int j = 0; j < 8; ++j) {
          int s = sb * 8 + j;
          #pragma unroll
          for (int vi = 0; vi < 4; ++vi) {
            float ubv = __builtin_bit_cast(float,
                __builtin_amdgcn_readlane(__builtin_bit_cast(int, u[vi]), s));
            u[vi] = fmaf(-Ac[j], ubv, u[vi]);
          }
        }
      }
      float sc = scU[lane];
      #pragma unroll
      for (int vi = 0; vi < 4; ++vi) {
        int v = w * 4 + vi;
        *(_Float16*)(Uvb + swz128(v, lane * 2)) = (_Float16)u[vi];
        *(_Float16*)(Ubb + swz128(v, lane * 2)) = (_Float16)(u[vi] * sc);
      }
    }
    __syncthreads();   // B3

    // ---- P4: O = (b.QS0) + M U -> global ; S-update (regs) + Sf f16 copy ----
    #pragma unroll
    for (int ss = 0; ss < 2; ++ss) {
      f16x8 aM = *(const f16x8*)(M16b + swz128(wr * 16 + la, ss * 64 + lk * 16));
      f16x8 bU = *(const f16x8*)(Uvb + swz128(wc * 16 + la, ss * 64 + lk * 16));
      qs0 = __builtin_amdgcn_mfma_f32_16x16x32_f16(aM, bU, qs0, 0, 0, 0);
    }
    #pragma unroll
    for (int r = 0; r < 4; ++r) {
      int t = wr * 16 + lk * 4 + r;
      vgb[(size_t)(c * 64 + t) * 4096 + wc * 16 + la] = (_Float16)qs0[r];  // in-place: v[t] dead
    }
    {
      f32x4 sd[2] = {};
      #pragma unroll
      for (int ss = 0; ss < 2; ++ss) {
        f16x8 bK = *(const f16x8*)(Ktb + swz128(w * 16 + la, ss * 64 + lk * 16));
        #pragma unroll
        for (int vt = 0; vt < 2; ++vt) {
          f16x8 aU = *(const f16x8*)(Ubb + swz128(vt * 16 + la, ss * 64 + lk * 16));
          sd[vt] = __builtin_amdgcn_mfma_f32_16x16x32_f16(aU, bK, sd[vt], 0, 0, 0);
        }
      }
      float beC = bexp[63];
      #pragma unroll
      for (int vt = 0; vt < 2; ++vt)
        #pragma unroll
        for (int r = 0; r < 4; ++r) {
          int v = vt * 16 + lk * 4 + r;
          int k = w * 16 + la;
          float sn = fmaf(sreg[vt][r], beC, sd[vt][r]);
          sreg[vt][r] = sn;
          *(_Float16*)(Sfb + swz256(v, k * 2)) = (_Float16)sn;
        }
    }
    __syncthreads();   // B4

    // ---- P5: write staged chunk c+1 into Ks/Qs/Vb/gs/bs ----
    *(f16x8*)(Ksb + swz256(srow, sseg * 32))      = kr[0];
    *(f16x8*)(Ksb + swz256(srow, sseg * 32 + 16)) = kr[1];
    *(f16x8*)(Qsb + swz256(srow, sseg * 32))      = qr[0];
    *(f16x8*)(Qsb + swz256(srow, sseg * 32 + 16)) = qr[1];
    *(f16x4*)(Vbb + srow * 64 + sseg * 8) = vr;
    if (tid < 64) gs[tid] = ebr; else if (tid < 128) bs[tid - 64] = ebr;
    __syncthreads();   // B5
  }
}

// ---------------- RMSNorm * norm_kernel * silu(z) -> fp16 Ag ----------------
__global__ __launch_bounds__(256)
void gate_kernel(const _Float16* __restrict__ ob, const _Float16* __restrict__ qkvz,
                 const float* __restrict__ nk, _Float16* __restrict__ Ag) {
  int row = blockIdx.x;
  int lane = threadIdx.x & 63, wid = threadIdx.x >> 6;
  for (int vh = wid; vh < 32; vh += 4) {
    const _Float16* op = ob + (size_t)row * 4096 + vh * 128;
    f16x2 xx = *(const f16x2*)(op + 2 * lane);
    float x0 = (float)xx[0], x1 = (float)xx[1];
    float ss = x0 * x0 + x1 * x1;
    #pragma unroll
    for (int m = 1; m < 64; m <<= 1) ss += __shfl_xor(ss, m);
    float rs = rsqrtf(ss * (1.f / 128.f) + 1e-6f);
    f32x2 nv = *(const f32x2*)(nk + 2 * lane);
    float v0 = x0 * rs * nv[0], v1 = x1 * rs * nv[1];
    const _Float16* zp = qkvz + (size_t)row * NQKV + (vh >> 1) * 768 + 512 + (vh & 1) * 128;
    f16x2 zz = *(const f16x2*)(zp + 2 * lane);
    float z0 = (float)zz[0], z1 = (float)zz[1];
    v0 *= z0 / (1.f + expf(-z0));
    v1 *= z1 / (1.f + expf(-z1));
    _Float16* dst = Ag + (size_t)row * 4096 + vh * 128;
    f16x2 o; o[0] = (_Float16)v0; o[1] = (_Float16)v1;
    *(f16x2*)(dst + 2 * lane) = o;
  }
}

extern "C" void kernel_launch(void* const* d_in, const int* in_sizes, int n_in,
                              void* d_out, int out_size, void* d_ws, size_t ws_size,
                              hipStream_t stream) {
  const float* h     = (const float*)d_in[0];
  const float* mask  = (const float*)d_in[1];
  const float* Wqkvz = (const float*)d_in[2];
  const float* Wba   = (const float*)d_in[3];
  const float* ck    = (const float*)d_in[4];
  const float* Alog  = (const float*)d_in[5];
  const float* dtb   = (const float*)d_in[6];
  const float* nk    = (const float*)d_in[7];
  const float* Wout  = (const float*)d_in[8];
  float* out = (float*)d_out;

  char* w = (char*)d_ws;
  const size_t o_qkvz = 0;                         // 100,663,296  [gemm1 .. gate]
  const size_t o_A1   = 100663296;                 //  16,777,216  [amask .. gemm1]
  const size_t o_Bt1  = o_A1 + 16777216;           //  50,331,648  [transpose .. gemm1]
  const size_t o_ba   = o_Bt1 + 50331648;          //   1,048,576
  const size_t o_g    = o_ba + 1048576;            //     524,288
  const size_t o_bt   = o_g + 524288;              //     524,288
  const size_t total  = o_bt + 524288;             // 169,869,312 B = 162 MiB
  if (ws_size < total) return;

  _Float16* qkvz16 = (_Float16*)(w + o_qkvz);
  _Float16* A1     = (_Float16*)(w + o_A1);
  _Float16* Bt1    = (_Float16*)(w + o_Bt1);
  float*    ba32   = (float*)   (w + o_ba);
  float*    gbuf   = (float*)   (w + o_g);
  float*    btb    = (float*)   (w + o_bt);
  // aliases over dead regions:
  _Float16* qn16 = (_Float16*)(w + o_A1);                    // over A1 (dead after gemm1)
  _Float16* kn16 = (_Float16*)(w + o_Bt1);                   // over Bt1[0:16M)
  _Float16* vb16 = (_Float16*)(w + o_Bt1 + 16777216);        // over Bt1[16M:50M); o in-place
  _Float16* Ag   = (_Float16*)(w + o_A1);                    // over qn+kn (dead after scan)
  _Float16* Wt2  = (_Float16*)(w + 0);                       // over qkvz (dead after gate)

  amask_kernel<<<MROWS * HIDD / 4 / 256, 256, 0, stream>>>(h, mask, A1);
  transpose_f16<<<dim3(192, 32), 256, 0, stream>>>(Wqkvz, Bt1, HIDD, NQKV);
  ba_gemm<<<MROWS / 8, 256, 0, stream>>>(h, mask, Wba, ba32);
  gemm_f16<_Float16><<<32 * 96, 256, 0, stream>>>(A1, Bt1, qkvz16, MROWS, NQKV, HIDD, 96);
  conv_kernel<<<MROWS, 256, 0, stream>>>(qkvz16, ck, qn16, kn16, vb16);
  egbeta_kernel<<<MROWS * 32 / 256, 256, 0, stream>>>(ba32, Alog, dtb, gbuf, btb);
  chunk_scan<<<256, 512, 0, stream>>>(qn16, kn16, vb16, gbuf, btb);
  gate_kernel<<<MROWS, 256, 0, stream>>>(vb16, qkvz16, nk, Ag);
  transpose_f16<<<dim3(32, 64), 256, 0, stream>>>(Wout, Wt2, 4096, HIDD);
  gemm_f16<float><<<32 * 16, 256, 0, stream>>>(Ag, Wt2, out, MROWS, HIDD, 4096, 16);
}

// Round 6
// 744.665 us; speedup vs baseline: 2.4352x; 1.0514x over previous
//
#include <hip/hip_runtime.h>
#include <stdint.h>

typedef float    f32x4 __attribute__((ext_vector_type(4)));
typedef float    f32x2 __attribute__((ext_vector_type(2)));
typedef _Float16 f16x8 __attribute__((ext_vector_type(8)));
typedef _Float16 f16x4 __attribute__((ext_vector_type(4)));
typedef _Float16 f16x2 __attribute__((ext_vector_type(2)));

#define SEQ   2048
#define HIDD  2048
#define MROWS 4096
#define NQKV  12288          // 96 x 128, no pad
#define NCHUNK 32
#define CLEN   64

__device__ __forceinline__ void gload_lds16(const void* g, void* l) {
  __builtin_amdgcn_global_load_lds((const __attribute__((address_space(1))) uint32_t*)g,
                                   (__attribute__((address_space(3))) uint32_t*)l, 16, 0, 0);
}
// XOR swizzles (byte addressing) for bank-conflict-free f16 frag reads
__device__ __forceinline__ int swz256(int row, int colb) { return row * 256 + (colb ^ ((row & 7) << 4)); }
__device__ __forceinline__ int swz128(int row, int colb) { return row * 128 + (colb ^ ((row & 7) << 4)); }

// ---------------- A = (h * mask) -> fp16 ----------------
__global__ __launch_bounds__(256)
void amask_kernel(const float* __restrict__ h, const float* __restrict__ mask,
                  _Float16* __restrict__ A1) {
  int i = blockIdx.x * 256 + threadIdx.x;            // one float4 each
  if (i >= MROWS * HIDD / 4) return;
  f32x4 x = ((const f32x4*)h)[i];
  float m = mask[(i * 4) >> 11];
  f16x4 r;
  r[0] = (_Float16)(x[0] * m); r[1] = (_Float16)(x[1] * m);
  r[2] = (_Float16)(x[2] * m); r[3] = (_Float16)(x[3] * m);
  *(f16x4*)(A1 + (size_t)i * 4) = r;
}

// ---------------- transpose fp32 [R][C] -> fp16 [C][R] ----------------
__global__ __launch_bounds__(256)
void transpose_f16(const float* __restrict__ in, _Float16* __restrict__ out,
                   int R, int C) {
  __shared__ float tile[64][65];
  int c0 = blockIdx.x * 64, r0 = blockIdx.y * 64;
  int tx = threadIdx.x & 63, ty = threadIdx.x >> 6;
  #pragma unroll
  for (int i = 0; i < 16; ++i) {
    int r = i * 4 + ty;
    tile[r][tx] = in[(size_t)(r0 + r) * C + c0 + tx];
  }
  __syncthreads();
  #pragma unroll
  for (int i = 0; i < 16; ++i) {
    int c = i * 4 + ty;
    out[(size_t)(c0 + c) * R + r0 + tx] = (_Float16)tile[tx][c];
  }
}

// ---------------- 256x256 / BK=64 / 8-wave double-buffered fp16 MFMA GEMM ----------------
// C[M][N] = A[M][K] * Bt[N][K]^T.  2-phase recipe: STAGE(next) issued early,
// ds_read+MFMA on current, single vmcnt(0)+barrier per K-tile.
// LDS rows linear (gload_lds-compatible); read conflicts fixed by PRE-SWIZZLING
// the per-lane GLOBAL source column with the same XOR used on the read side.
template <typename CT>
__global__ __launch_bounds__(512, 2)
void gemm256(const _Float16* __restrict__ A, const _Float16* __restrict__ Bt,
             CT* __restrict__ C, int M, int N, int K, int tiles_n) {
  __shared__ __align__(16) _Float16 lsA[2][256 * 64];   // [buf][row][64 halves = 128B]
  __shared__ __align__(16) _Float16 lsB[2][256 * 64];
  int bm = blockIdx.x / tiles_n, bn = blockIdx.x % tiles_n;
  int m0 = bm * 256, n0 = bn * 256;
  int tid = threadIdx.x;
  int w = tid >> 6, lane = tid & 63;
  int wm = w >> 2, wn = w & 3;            // wave tile: rows [wm*128,+128), cols [wn*64,+64)
  int la = lane & 15, lk = lane >> 4;
  int sr = lane >> 3;                               // slab row 0..7
  int scb = ((lane & 7) << 4) ^ ((sr & 7) << 4);    // pre-swizzled source byte col
  int nkt = K >> 6;
  f32x4 acc[8][4] = {};

  // prologue: stage K-tile 0 into buf 0 (wave w covers rows [w*32, w*32+32))
  {
    const char* ga = (const char*)(A  + (size_t)(m0 + w * 32) * K);
    const char* gb = (const char*)(Bt + (size_t)(n0 + w * 32) * K);
    #pragma unroll
    for (int i = 0; i < 4; ++i) {
      gload_lds16(ga + (size_t)(i * 8 + sr) * (K * 2) + scb, &lsA[0][(w * 32 + i * 8) * 64]);
      gload_lds16(gb + (size_t)(i * 8 + sr) * (K * 2) + scb, &lsB[0][(w * 32 + i * 8) * 64]);
    }
  }
  __syncthreads();

  int cur = 0;
  for (int kt = 0; kt < nkt; ++kt) {
    if (kt + 1 < nkt) {   // issue next-tile staging BEFORE compute (overlaps with MFMA)
      const char* ga = (const char*)(A  + (size_t)(m0 + w * 32) * K + (kt + 1) * 64);
      const char* gb = (const char*)(Bt + (size_t)(n0 + w * 32) * K + (kt + 1) * 64);
      #pragma unroll
      for (int i = 0; i < 4; ++i) {
        gload_lds16(ga + (size_t)(i * 8 + sr) * (K * 2) + scb, &lsA[cur ^ 1][(w * 32 + i * 8) * 64]);
        gload_lds16(gb + (size_t)(i * 8 + sr) * (K * 2) + scb, &lsB[cur ^ 1][(w * 32 + i * 8) * 64]);
      }
    }
    const char* cA = (const char*)&lsA[cur][0];
    const char* cB = (const char*)&lsB[cur][0];
    #pragma unroll
    for (int kw = 0; kw < 2; ++kw) {
      f16x8 af[8], bf[4];
      #pragma unroll
      for (int f = 0; f < 8; ++f) {
        int row = wm * 128 + f * 16 + la;
        af[f] = *(const f16x8*)(cA + row * 128 + ((kw * 64 + lk * 16) ^ ((row & 7) << 4)));
      }
      #pragma unroll
      for (int j = 0; j < 4; ++j) {
        int row = wn * 64 + j * 16 + la;
        bf[j] = *(const f16x8*)(cB + row * 128 + ((kw * 64 + lk * 16) ^ ((row & 7) << 4)));
      }
      #pragma unroll
      for (int f = 0; f < 8; ++f)
        #pragma unroll
        for (int j = 0; j < 4; ++j)
          acc[f][j] = __builtin_amdgcn_mfma_f32_16x16x32_f16(af[f], bf[j], acc[f][j], 0, 0, 0);
    }
    __syncthreads();      // drains this tile's reads + all waves' staging loads
    cur ^= 1;
  }

  #pragma unroll
  for (int f = 0; f < 8; ++f)
    #pragma unroll
    for (int j = 0; j < 4; ++j) {
      int col = n0 + wn * 64 + j * 16 + la;
      #pragma unroll
      for (int r = 0; r < 4; ++r) {
        int row = m0 + wm * 128 + f * 16 + lk * 4 + r;
        C[(size_t)row * N + col] = (CT)acc[f][j][r];
      }
    }
}

// ---------------- ba = (h*mask) @ W_ba in fp32 (precision-critical for g) ----------------
__global__ __launch_bounds__(256)
void ba_gemm(const float* __restrict__ h, const float* __restrict__ mask,
             const float* __restrict__ Wba, float* __restrict__ ba) {
  __shared__ float red[4][8][64];
  int r0 = blockIdx.x * 8;
  int c = threadIdx.x & 63, kc = threadIdx.x >> 6;
  float acc[8] = {};
  const float* wp = Wba + (size_t)(kc * 512) * 64 + c;
  const float* hp = h + (size_t)r0 * HIDD + kc * 512;
  for (int i = 0; i < 512; ++i) {
    float w = wp[(size_t)i * 64];
    #pragma unroll
    for (int r = 0; r < 8; ++r)
      acc[r] += hp[(size_t)r * HIDD + i] * w;
  }
  #pragma unroll
  for (int r = 0; r < 8; ++r) red[kc][r][c] = acc[r];
  __syncthreads();
  if (kc == 0) {
    #pragma unroll
    for (int r = 0; r < 8; ++r) {
      float s = red[0][r][c] + red[1][r][c] + red[2][r][c] + red[3][r][c];
      ba[(size_t)(r0 + r) * 64 + c] = s * mask[r0 + r];
    }
  }
}

// ---------------- conv(4-tap causal) + SiLU + l2norm -> qn16, kn16, vb16 ----------------
__global__ __launch_bounds__(256)
void conv_kernel(const _Float16* __restrict__ qkvz, const float* __restrict__ ck,
                 _Float16* __restrict__ qn, _Float16* __restrict__ kn,
                 _Float16* __restrict__ vb) {
  int row = blockIdx.x;               // b*2048 + t
  int b = row >> 11, t = row & 2047;
  int lane = threadIdx.x & 63, wid = threadIdx.x >> 6;
  for (int u = wid; u < 64; u += 4) {
    int c, cc, hh;
    if (u < 16)      { hh = u;      c = hh * 768;                               cc = hh * 128; }
    else if (u < 32) { hh = u - 16; c = hh * 768 + 128;                         cc = 2048 + hh * 128; }
    else             { hh = u - 32; c = (hh >> 1) * 768 + 256 + (hh & 1) * 128; cc = 4096 + hh * 128; }
    float y0 = 0.f, y1 = 0.f;
    #pragma unroll
    for (int j = 0; j < 4; ++j) {
      int tt = t - 3 + j;
      if (tt >= 0) {
        const _Float16* r = qkvz + (size_t)(b * 2048 + tt) * NQKV + c;
        f16x2 x = *(const f16x2*)(r + 2 * lane);
        f32x2 w = *(const f32x2*)(ck + j * 8192 + cc + 2 * lane);
        y0 += (float)x[0] * w[0];
        y1 += (float)x[1] * w[1];
      }
    }
    y0 = y0 / (1.f + expf(-y0));
    y1 = y1 / (1.f + expf(-y1));
    if (u < 32) {
      float ss = y0 * y0 + y1 * y1;
      #pragma unroll
      for (int m = 1; m < 64; m <<= 1) ss += __shfl_xor(ss, m);
      float rs = rsqrtf(ss + 1e-6f);
      if (u < 16) rs *= 0.08838834764831845f;   // DK^-0.5
      y0 *= rs; y1 *= rs;
      _Float16* dst = (u < 16 ? qn : kn) + (size_t)row * 2048 + hh * 128;
      f16x2 o; o[0] = (_Float16)y0; o[1] = (_Float16)y1;
      *(f16x2*)(dst + 2 * lane) = o;
    } else {
      _Float16* dst = vb + (size_t)row * 4096 + hh * 128;
      f16x2 o; o[0] = (_Float16)y0; o[1] = (_Float16)y1;
      *(f16x2*)(dst + 2 * lane) = o;
    }
  }
}

// ---------------- g/beta from fp32 ba; outputs TRANSPOSED [vh][b*2048+t] ----------------
__global__ __launch_bounds__(256)
void egbeta_kernel(const float* __restrict__ ba, const float* __restrict__ Alog,
                   const float* __restrict__ dtb, float* __restrict__ gout,
                   float* __restrict__ bout) {
  int i = blockIdx.x * 256 + threadIdx.x;     // MROWS*32
  if (i >= MROWS * 32) return;
  int vh = i >> 12, row = i & 4095;
  int kh = vh >> 1, r = vh & 1;
  const float* p = ba + (size_t)row * 64 + kh * 4;
  float bv = p[r], av = p[2 + r];
  float x = av + dtb[vh];
  float sp = (x > 20.f) ? x : log1pf(expf(x));
  gout[(size_t)vh * MROWS + row] = -expf(Alog[vh]) * sp;
  bout[(size_t)vh * MROWS + row] = 1.f / (1.f + expf(-bv));
}

// ---------------- chunked gated delta-rule scan (UT transform, MFMA, 8 waves) ----------------
__global__ __launch_bounds__(512, 2)
void chunk_scan(const _Float16* __restrict__ qn, const _Float16* __restrict__ kn,
                _Float16* __restrict__ vb, const float* __restrict__ gb,
                const float* __restrict__ btb) {
  __shared__ __align__(16) _Float16 Ks[64 * 128];   // [t][k] swz256
  __shared__ __align__(16) _Float16 Qs[64 * 128];   // [t][k] swz256
  __shared__ __align__(16) _Float16 Kt[128 * 64];   // [k][s] swz128
  __shared__ __align__(16) _Float16 Sf[32 * 128];   // [v][k] f16 state copy, swz256
  __shared__ float AT[64 * 65];                     // AT[s][t] = A[t][s]
  __shared__ __align__(16) _Float16 M16[64 * 64];   // [t][s] swz128
  __shared__ float RHS[32 * 65];                    // [v][t]
  __shared__ __align__(16) _Float16 Uv[32 * 64];    // [v][s] swz128 (raw u)
  __shared__ __align__(16) _Float16 Ub[32 * 64];    // [v][s] swz128 (u * scU[s])
  __shared__ __align__(16) _Float16 Vb[64 * 32];    // [t][v] linear, 64B rows
  __shared__ float gs[64], bs[64], cgs[64], bexp[64], scU[64];

  char* Ksb = (char*)Ks; char* Qsb = (char*)Qs; char* Ktb = (char*)Kt;
  char* Sfb = (char*)Sf; char* M16b = (char*)M16;
  char* Uvb = (char*)Uv; char* Ubb = (char*)Ub; char* Vbb = (char*)Vb;

  int bid = blockIdx.x;
  int b = bid >> 7, vh = (bid >> 2) & 31, vsl = bid & 3;
  int kh = vh >> 1;
  int tid = threadIdx.x;
  int w = tid >> 6, lane = tid & 63;
  int wr = w >> 1, wc = w & 1;
  int la = lane & 15, lk = lane >> 4;

  const _Float16* kgb = kn + (size_t)(b * 2048) * 2048 + kh * 128;
  const _Float16* qgb = qn + (size_t)(b * 2048) * 2048 + kh * 128;
  _Float16*       vgb = vb + (size_t)(b * 2048) * 4096 + vh * 128 + vsl * 32;
  const float*    ggb = gb  + (size_t)vh * MROWS + b * 2048;
  const float*    bgb = btb + (size_t)vh * MROWS + b * 2048;

  int srow = tid >> 3, sseg = tid & 7;
  int tk = tid & 127, tth = tid >> 7;

  f16x8 kr[2], qr[2]; f16x4 vr; float ebr;
  float sreg[2][4] = {};                 // S[v = vt*16+lk*4+r][k = w*16+la]

  { f32x4 z = {}; ((f32x4*)Sf)[tid] = z; }

  kr[0] = *(const f16x8*)(kgb + (size_t)srow * 2048 + sseg * 16);
  kr[1] = *(const f16x8*)(kgb + (size_t)srow * 2048 + sseg * 16 + 8);
  qr[0] = *(const f16x8*)(qgb + (size_t)srow * 2048 + sseg * 16);
  qr[1] = *(const f16x8*)(qgb + (size_t)srow * 2048 + sseg * 16 + 8);
  vr    = *(const f16x4*)(vgb + (size_t)srow * 4096 + sseg * 4);
  ebr   = (tid < 64) ? ggb[tid] : (tid < 128 ? bgb[tid - 64] : 0.f);
  *(f16x8*)(Ksb + swz256(srow, sseg * 32))      = kr[0];
  *(f16x8*)(Ksb + swz256(srow, sseg * 32 + 16)) = kr[1];
  *(f16x8*)(Qsb + swz256(srow, sseg * 32))      = qr[0];
  *(f16x8*)(Qsb + swz256(srow, sseg * 32 + 16)) = qr[1];
  *(f16x4*)(Vbb + srow * 64 + sseg * 8) = vr;
  if (tid < 64) gs[tid] = ebr; else if (tid < 128) bs[tid - 64] = ebr;
  __syncthreads();

  #pragma unroll 1
  for (int c = 0; c < NCHUNK; ++c) {
    int cn = (c < NCHUNK - 1) ? c + 1 : c;
    kr[0] = *(const f16x8*)(kgb + (size_t)(cn * 64 + srow) * 2048 + sseg * 16);
    kr[1] = *(const f16x8*)(kgb + (size_t)(cn * 64 + srow) * 2048 + sseg * 16 + 8);
    qr[0] = *(const f16x8*)(qgb + (size_t)(cn * 64 + srow) * 2048 + sseg * 16);
    qr[1] = *(const f16x8*)(qgb + (size_t)(cn * 64 + srow) * 2048 + sseg * 16 + 8);
    vr    = *(const f16x4*)(vgb + (size_t)(cn * 64 + srow) * 4096 + sseg * 4);
    ebr   = (tid < 64) ? ggb[cn * 64 + tid] : (tid < 128 ? bgb[cn * 64 + tid - 64] : 0.f);

    f32x4 kk[2] = {}, qk[2] = {}, ks0 = {}, qs0 = {};
    #pragma unroll
    for (int ks = 0; ks < 4; ++ks) {
      f16x8 aK = *(const f16x8*)(Ksb + swz256(wr * 16 + la, ks * 64 + lk * 16));
      f16x8 aQ = *(const f16x8*)(Qsb + swz256(wr * 16 + la, ks * 64 + lk * 16));
      f16x8 bS = *(const f16x8*)(Sfb + swz256(wc * 16 + la, ks * 64 + lk * 16));
      #pragma unroll
      for (int j = 0; j < 2; ++j) {
        f16x8 bK = *(const f16x8*)(Ksb + swz256(wc * 32 + j * 16 + la, ks * 64 + lk * 16));
        kk[j] = __builtin_amdgcn_mfma_f32_16x16x32_f16(aK, bK, kk[j], 0, 0, 0);
        qk[j] = __builtin_amdgcn_mfma_f32_16x16x32_f16(aQ, bK, qk[j], 0, 0, 0);
      }
      ks0 = __builtin_amdgcn_mfma_f32_16x16x32_f16(aK, bS, ks0, 0, 0, 0);
      qs0 = __builtin_amdgcn_mfma_f32_16x16x32_f16(aQ, bS, qs0, 0, 0, 0);
    }
    {
      f16x8 r0, r1;
      #pragma unroll
      for (int j = 0; j < 8; ++j) {
        r0[j] = *(const _Float16*)(Ksb + swz256(tth * 16 + j, 2 * tk));
        r1[j] = *(const _Float16*)(Ksb + swz256(tth * 16 + 8 + j, 2 * tk));
      }
      *(f16x8*)(Ktb + swz128(tk, tth * 32))      = r0;
      *(f16x8*)(Ktb + swz128(tk, tth * 32 + 16)) = r1;
    }
    if (w == 0) {
      float g = gs[lane];
      #pragma unroll
      for (int off = 1; off < 64; off <<= 1) {
        float y = __shfl_up(g, off);
        if (lane >= off) g += y;
      }
      cgs[lane] = g;
      float cgL = __shfl(g, 63);
      bexp[lane] = __expf(g);
      scU[lane] = bs[lane] * __expf(cgL - g);
    }
    __syncthreads();   // B1

    {
      float cgt[4];
      #pragma unroll
      for (int r = 0; r < 4; ++r) cgt[r] = cgs[wr * 16 + lk * 4 + r];
      #pragma unroll
      for (int j = 0; j < 2; ++j) {
        int s = wc * 32 + j * 16 + la;
        float bsv = bs[s], cgss = cgs[s];
        #pragma unroll
        for (int r = 0; r < 4; ++r) {
          int t = wr * 16 + lk * 4 + r;
          float e = bsv * __expf(cgt[r] - cgss);
          AT[s * 65 + t] = (s < t) ? e * kk[j][r] : 0.f;
          float mm = (s <= t) ? e * qk[j][r] : 0.f;
          *(_Float16*)(M16b + swz128(t, s * 2)) = (_Float16)mm;
        }
      }
      #pragma unroll
      for (int r = 0; r < 4; ++r) {
        int t = wr * 16 + lk * 4 + r;
        int v = wc * 16 + la;
        float be = bexp[t];
        qs0[r] *= be;
        float vv = (float)*(const _Float16*)(Vbb + t * 64 + v * 2);
        RHS[v * 65 + t] = vv - be * ks0[r];
      }
    }
    __syncthreads();   // B2

    {
      float u[4];
      #pragma unroll
      for (int vi = 0; vi < 4; ++vi) u[vi] = RHS[(w * 4 + vi) * 65 + lane];
      #pragma unroll 1
      for (int sb = 0; sb < 8; ++sb) {
        float Ac[8];
        #pragma unroll
        for (int j = 0; j < 8; ++j) Ac[j] = AT[(sb * 8 + j) * 65 + lane];
        #pragma unroll
        for (int j = 0; j < 8; ++j) {
          int s = sb * 8 + j;
          #pragma unroll
          for (int vi = 0; vi < 4; ++vi) {
            float ubv = __builtin_bit_cast(float,
                __builtin_amdgcn_readlane(__builtin_bit_cast(int, u[vi]), s));
            u[vi] = fmaf(-Ac[j], ubv, u[vi]);
          }
        }
      }
      float sc = scU[lane];
      #pragma unroll
      for (int vi = 0; vi < 4; ++vi) {
        int v = w * 4 + vi;
        *(_Float16*)(Uvb + swz128(v, lane * 2)) = (_Float16)u[vi];
        *(_Float16*)(Ubb + swz128(v, lane * 2)) = (_Float16)(u[vi] * sc);
      }
    }
    __syncthreads();   // B3

    #pragma unroll
    for (int ss = 0; ss < 2; ++ss) {
      f16x8 aM = *(const f16x8*)(M16b + swz128(wr * 16 + la, ss * 64 + lk * 16));
      f16x8 bU = *(const f16x8*)(Uvb + swz128(wc * 16 + la, ss * 64 + lk * 16));
      qs0 = __builtin_amdgcn_mfma_f32_16x16x32_f16(aM, bU, qs0, 0, 0, 0);
    }
    #pragma unroll
    for (int r = 0; r < 4; ++r) {
      int t = wr * 16 + lk * 4 + r;
      vgb[(size_t)(c * 64 + t) * 4096 + wc * 16 + la] = (_Float16)qs0[r];  // in-place: v[t] dead
    }
    {
      f32x4 sd[2] = {};
      #pragma unroll
      for (int ss = 0; ss < 2; ++ss) {
        f16x8 bK = *(const f16x8*)(Ktb + swz128(w * 16 + la, ss * 64 + lk * 16));
        #pragma unroll
        for (int vt = 0; vt < 2; ++vt) {
          f16x8 aU = *(const f16x8*)(Ubb + swz128(vt * 16 + la, ss * 64 + lk * 16));
          sd[vt] = __builtin_amdgcn_mfma_f32_16x16x32_f16(aU, bK, sd[vt], 0, 0, 0);
        }
      }
      float beC = bexp[63];
      #pragma unroll
      for (int vt = 0; vt < 2; ++vt)
        #pragma unroll
        for (int r = 0; r < 4; ++r) {
          int v = vt * 16 + lk * 4 + r;
          int k = w * 16 + la;
          float sn = fmaf(sreg[vt][r], beC, sd[vt][r]);
          sreg[vt][r] = sn;
          *(_Float16*)(Sfb + swz256(v, k * 2)) = (_Float16)sn;
        }
    }
    __syncthreads();   // B4

    *(f16x8*)(Ksb + swz256(srow, sseg * 32))      = kr[0];
    *(f16x8*)(Ksb + swz256(srow, sseg * 32 + 16)) = kr[1];
    *(f16x8*)(Qsb + swz256(srow, sseg * 32))      = qr[0];
    *(f16x8*)(Qsb + swz256(srow, sseg * 32 + 16)) = qr[1];
    *(f16x4*)(Vbb + srow * 64 + sseg * 8) = vr;
    if (tid < 64) gs[tid] = ebr; else if (tid < 128) bs[tid - 64] = ebr;
    __syncthreads();   // B5
  }
}

// ---------------- RMSNorm * norm_kernel * silu(z) -> fp16 Ag ----------------
__global__ __launch_bounds__(256)
void gate_kernel(const _Float16* __restrict__ ob, const _Float16* __restrict__ qkvz,
                 const float* __restrict__ nk, _Float16* __restrict__ Ag) {
  int row = blockIdx.x;
  int lane = threadIdx.x & 63, wid = threadIdx.x >> 6;
  for (int vh = wid; vh < 32; vh += 4) {
    const _Float16* op = ob + (size_t)row * 4096 + vh * 128;
    f16x2 xx = *(const f16x2*)(op + 2 * lane);
    float x0 = (float)xx[0], x1 = (float)xx[1];
    float ss = x0 * x0 + x1 * x1;
    #pragma unroll
    for (int m = 1; m < 64; m <<= 1) ss += __shfl_xor(ss, m);
    float rs = rsqrtf(ss * (1.f / 128.f) + 1e-6f);
    f32x2 nv = *(const f32x2*)(nk + 2 * lane);
    float v0 = x0 * rs * nv[0], v1 = x1 * rs * nv[1];
    const _Float16* zp = qkvz + (size_t)row * NQKV + (vh >> 1) * 768 + 512 + (vh & 1) * 128;
    f16x2 zz = *(const f16x2*)(zp + 2 * lane);
    float z0 = (float)zz[0], z1 = (float)zz[1];
    v0 *= z0 / (1.f + expf(-z0));
    v1 *= z1 / (1.f + expf(-z1));
    _Float16* dst = Ag + (size_t)row * 4096 + vh * 128;
    f16x2 o; o[0] = (_Float16)v0; o[1] = (_Float16)v1;
    *(f16x2*)(dst + 2 * lane) = o;
  }
}

extern "C" void kernel_launch(void* const* d_in, const int* in_sizes, int n_in,
                              void* d_out, int out_size, void* d_ws, size_t ws_size,
                              hipStream_t stream) {
  const float* h     = (const float*)d_in[0];
  const float* mask  = (const float*)d_in[1];
  const float* Wqkvz = (const float*)d_in[2];
  const float* Wba   = (const float*)d_in[3];
  const float* ck    = (const float*)d_in[4];
  const float* Alog  = (const float*)d_in[5];
  const float* dtb   = (const float*)d_in[6];
  const float* nk    = (const float*)d_in[7];
  const float* Wout  = (const float*)d_in[8];
  float* out = (float*)d_out;

  char* w = (char*)d_ws;
  const size_t o_qkvz = 0;                         // 100,663,296  [gemm1 .. gate]
  const size_t o_A1   = 100663296;                 //  16,777,216  [amask .. gemm1]
  const size_t o_Bt1  = o_A1 + 16777216;           //  50,331,648  [transpose .. gemm1]
  const size_t o_ba   = o_Bt1 + 50331648;          //   1,048,576
  const size_t o_g    = o_ba + 1048576;            //     524,288
  const size_t o_bt   = o_g + 524288;              //     524,288
  const size_t total  = o_bt + 524288;             // 169,869,312 B = 162 MiB
  if (ws_size < total) return;

  _Float16* qkvz16 = (_Float16*)(w + o_qkvz);
  _Float16* A1     = (_Float16*)(w + o_A1);
  _Float16* Bt1    = (_Float16*)(w + o_Bt1);
  float*    ba32   = (float*)   (w + o_ba);
  float*    gbuf   = (float*)   (w + o_g);
  float*    btb    = (float*)   (w + o_bt);
  // aliases over dead regions:
  _Float16* qn16 = (_Float16*)(w + o_A1);                    // over A1 (dead after gemm1)
  _Float16* kn16 = (_Float16*)(w + o_Bt1);                   // over Bt1[0:16M)
  _Float16* vb16 = (_Float16*)(w + o_Bt1 + 16777216);        // over Bt1[16M:50M); o in-place
  _Float16* Ag   = (_Float16*)(w + o_A1);                    // over qn+kn (dead after scan)
  _Float16* Wt2  = (_Float16*)(w + 0);                       // over qkvz (dead after gate)

  amask_kernel<<<MROWS * HIDD / 4 / 256, 256, 0, stream>>>(h, mask, A1);
  transpose_f16<<<dim3(192, 32), 256, 0, stream>>>(Wqkvz, Bt1, HIDD, NQKV);
  ba_gemm<<<MROWS / 8, 256, 0, stream>>>(h, mask, Wba, ba32);
  gemm256<_Float16><<<16 * 48, 512, 0, stream>>>(A1, Bt1, qkvz16, MROWS, NQKV, HIDD, 48);
  conv_kernel<<<MROWS, 256, 0, stream>>>(qkvz16, ck, qn16, kn16, vb16);
  egbeta_kernel<<<MROWS * 32 / 256, 256, 0, stream>>>(ba32, Alog, dtb, gbuf, btb);
  chunk_scan<<<256, 512, 0, stream>>>(qn16, kn16, vb16, gbuf, btb);
  gate_kernel<<<MROWS, 256, 0, stream>>>(vb16, qkvz16, nk, Ag);
  transpose_f16<<<dim3(32, 64), 256, 0, stream>>>(Wout, Wt2, 4096, HIDD);
  gemm256<float><<<16 * 8, 512, 0, stream>>>(Ag, Wt2, out, MROWS, HIDD, 4096, 8);
}

// Round 7
// 700.170 us; speedup vs baseline: 2.5900x; 1.0635x over previous
//
#include <hip/hip_runtime.h>
#include <stdint.h>

typedef float    f32x4 __attribute__((ext_vector_type(4)));
typedef float    f32x2 __attribute__((ext_vector_type(2)));
typedef _Float16 f16x8 __attribute__((ext_vector_type(8)));
typedef _Float16 f16x4 __attribute__((ext_vector_type(4)));
typedef _Float16 f16x2 __attribute__((ext_vector_type(2)));

#define SEQ   2048
#define HIDD  2048
#define MROWS 4096
#define NQKV  12288          // 96 x 128, no pad
#define NCHUNK 32
#define CLEN   64

__device__ __forceinline__ void gload_lds16(const void* g, void* l) {
  __builtin_amdgcn_global_load_lds((const __attribute__((address_space(1))) uint32_t*)g,
                                   (__attribute__((address_space(3))) uint32_t*)l, 16, 0, 0);
}
// XOR swizzles (byte addressing) for bank-conflict-free f16 frag reads
__device__ __forceinline__ int swz256(int row, int colb) { return row * 256 + (colb ^ ((row & 7) << 4)); }
__device__ __forceinline__ int swz128(int row, int colb) { return row * 128 + (colb ^ ((row & 7) << 4)); }

// ---------------- A = (h * mask) -> fp16 ----------------
__global__ __launch_bounds__(256)
void amask_kernel(const float* __restrict__ h, const float* __restrict__ mask,
                  _Float16* __restrict__ A1) {
  int i = blockIdx.x * 256 + threadIdx.x;            // one float4 each
  if (i >= MROWS * HIDD / 4) return;
  f32x4 x = ((const f32x4*)h)[i];
  float m = mask[(i * 4) >> 11];
  f16x4 r;
  r[0] = (_Float16)(x[0] * m); r[1] = (_Float16)(x[1] * m);
  r[2] = (_Float16)(x[2] * m); r[3] = (_Float16)(x[3] * m);
  *(f16x4*)(A1 + (size_t)i * 4) = r;
}

// ---------------- transpose fp32 [R][C] -> fp16 [C][R] ----------------
__global__ __launch_bounds__(256)
void transpose_f16(const float* __restrict__ in, _Float16* __restrict__ out,
                   int R, int C) {
  __shared__ float tile[64][65];
  int c0 = blockIdx.x * 64, r0 = blockIdx.y * 64;
  int tx = threadIdx.x & 63, ty = threadIdx.x >> 6;
  #pragma unroll
  for (int i = 0; i < 16; ++i) {
    int r = i * 4 + ty;
    tile[r][tx] = in[(size_t)(r0 + r) * C + c0 + tx];
  }
  __syncthreads();
  #pragma unroll
  for (int i = 0; i < 16; ++i) {
    int c = i * 4 + ty;
    out[(size_t)(c0 + c) * R + r0 + tx] = (_Float16)tile[tx][c];
  }
}

// ---------------- BMx256 / BK=64 / 8-wave fp16 MFMA GEMM, counted-vmcnt pipeline ----
// C[M][N] = A[M][K] * Bt[N][K]^T.
// Per iter: wait vmcnt(STG) [tile-kt loads done, kt+1's stay in flight]; barrier;
// ds_read+MFMA on buf[cur]; barrier [reads done]; STAGE(kt+2) -> buf[cur].
// LDS rows linear (gload_lds dest); read conflicts fixed by PRE-SWIZZLING the
// per-lane GLOBAL source column with the same XOR used on the read side.
template <typename CT, int BM>
__global__ __launch_bounds__(512, 2)
void gemm2ph(const _Float16* __restrict__ A, const _Float16* __restrict__ Bt,
             CT* __restrict__ C, int M, int N, int K, int tiles_n) {
  constexpr int RF  = BM / 32;          // row frags per wave (8 or 4)
  constexpr int AR  = BM / 8;           // A rows staged per wave (32 or 16)
  constexpr int NA  = AR / 8;           // A stage insts per thread (4 or 2)
  constexpr int STG = NA + 4;           // stage insts per thread per K-tile
  __shared__ __align__(16) _Float16 lsA[2][BM * 64];
  __shared__ __align__(16) _Float16 lsB[2][256 * 64];
  int bm = blockIdx.x / tiles_n, bn = blockIdx.x % tiles_n;
  int m0 = bm * BM, n0 = bn * 256;
  int tid = threadIdx.x;
  int w = tid >> 6, lane = tid & 63;
  int wm = w >> 2, wn = w & 3;          // wave tile: rows [wm*(BM/2),+BM/2), cols [wn*64,+64)
  int la = lane & 15, lk = lane >> 4;
  int sr = lane >> 3;                               // slab row 0..7
  int scb = ((lane & 7) << 4) ^ ((sr & 7) << 4);    // pre-swizzled source byte col
  int nkt = K >> 6;
  f32x4 acc[RF][4] = {};

  auto stage = [&](int kt, int buf) {
    const char* ga = (const char*)(A  + (size_t)(m0 + w * AR) * K + kt * 64);
    const char* gb = (const char*)(Bt + (size_t)(n0 + w * 32) * K + kt * 64);
    #pragma unroll
    for (int i = 0; i < NA; ++i)
      gload_lds16(ga + (size_t)(i * 8 + sr) * (K * 2) + scb, &lsA[buf][(w * AR + i * 8) * 64]);
    #pragma unroll
    for (int i = 0; i < 4; ++i)
      gload_lds16(gb + (size_t)(i * 8 + sr) * (K * 2) + scb, &lsB[buf][(w * 32 + i * 8) * 64]);
  };

  stage(0, 0);
  if (nkt > 1) stage(1, 1);

  int cur = 0;
  for (int kt = 0; kt < nkt; ++kt) {
    if (kt < nkt - 1) asm volatile("s_waitcnt vmcnt(%0)" :: "i"(STG) : "memory");
    else              asm volatile("s_waitcnt vmcnt(0)" ::: "memory");
    __builtin_amdgcn_s_barrier();       // buf[cur] fully written by all waves
    const char* cA = (const char*)&lsA[cur][0];
    const char* cB = (const char*)&lsB[cur][0];
    #pragma unroll
    for (int kw = 0; kw < 2; ++kw) {
      f16x8 af[RF], bf[4];
      #pragma unroll
      for (int f = 0; f < RF; ++f) {
        int row = wm * (BM / 2) + f * 16 + la;
        af[f] = *(const f16x8*)(cA + row * 128 + ((kw * 64 + lk * 16) ^ ((row & 7) << 4)));
      }
      #pragma unroll
      for (int j = 0; j < 4; ++j) {
        int row = wn * 64 + j * 16 + la;
        bf[j] = *(const f16x8*)(cB + row * 128 + ((kw * 64 + lk * 16) ^ ((row & 7) << 4)));
      }
      #pragma unroll
      for (int f = 0; f < RF; ++f)
        #pragma unroll
        for (int j = 0; j < 4; ++j)
          acc[f][j] = __builtin_amdgcn_mfma_f32_16x16x32_f16(af[f], bf[j], acc[f][j], 0, 0, 0);
    }
    __builtin_amdgcn_s_barrier();       // all waves done reading buf[cur]
    if (kt + 2 < nkt) stage(kt + 2, cur);   // safe: lands in buf[cur] after barrier
    cur ^= 1;
  }

  #pragma unroll
  for (int f = 0; f < RF; ++f)
    #pragma unroll
    for (int j = 0; j < 4; ++j) {
      int col = n0 + wn * 64 + j * 16 + la;
      #pragma unroll
      for (int r = 0; r < 4; ++r) {
        int row = m0 + wm * (BM / 2) + f * 16 + lk * 4 + r;
        C[(size_t)row * N + col] = (CT)acc[f][j][r];
      }
    }
}

// ---------------- ba = (h*mask) @ W_ba in fp32 (precision-critical for g) ----------------
__global__ __launch_bounds__(256)
void ba_gemm(const float* __restrict__ h, const float* __restrict__ mask,
             const float* __restrict__ Wba, float* __restrict__ ba) {
  __shared__ float red[4][8][64];
  int r0 = blockIdx.x * 8;
  int c = threadIdx.x & 63, kc = threadIdx.x >> 6;
  float acc[8] = {};
  const float* wp = Wba + (size_t)(kc * 512) * 64 + c;
  const float* hp = h + (size_t)r0 * HIDD + kc * 512;
  for (int i = 0; i < 512; ++i) {
    float w = wp[(size_t)i * 64];
    #pragma unroll
    for (int r = 0; r < 8; ++r)
      acc[r] += hp[(size_t)r * HIDD + i] * w;
  }
  #pragma unroll
  for (int r = 0; r < 8; ++r) red[kc][r][c] = acc[r];
  __syncthreads();
  if (kc == 0) {
    #pragma unroll
    for (int r = 0; r < 8; ++r) {
      float s = red[0][r][c] + red[1][r][c] + red[2][r][c] + red[3][r][c];
      ba[(size_t)(r0 + r) * 64 + c] = s * mask[r0 + r];
    }
  }
}

// ---------------- conv(4-tap causal) + SiLU + l2norm -> qn16, kn16, vb16 ----------------
__global__ __launch_bounds__(256)
void conv_kernel(const _Float16* __restrict__ qkvz, const float* __restrict__ ck,
                 _Float16* __restrict__ qn, _Float16* __restrict__ kn,
                 _Float16* __restrict__ vb) {
  int row = blockIdx.x;               // b*2048 + t
  int b = row >> 11, t = row & 2047;
  int lane = threadIdx.x & 63, wid = threadIdx.x >> 6;
  for (int u = wid; u < 64; u += 4) {
    int c, cc, hh;
    if (u < 16)      { hh = u;      c = hh * 768;                               cc = hh * 128; }
    else if (u < 32) { hh = u - 16; c = hh * 768 + 128;                         cc = 2048 + hh * 128; }
    else             { hh = u - 32; c = (hh >> 1) * 768 + 256 + (hh & 1) * 128; cc = 4096 + hh * 128; }
    float y0 = 0.f, y1 = 0.f;
    #pragma unroll
    for (int j = 0; j < 4; ++j) {
      int tt = t - 3 + j;
      if (tt >= 0) {
        const _Float16* r = qkvz + (size_t)(b * 2048 + tt) * NQKV + c;
        f16x2 x = *(const f16x2*)(r + 2 * lane);
        f32x2 w = *(const f32x2*)(ck + j * 8192 + cc + 2 * lane);
        y0 += (float)x[0] * w[0];
        y1 += (float)x[1] * w[1];
      }
    }
    y0 = y0 / (1.f + expf(-y0));
    y1 = y1 / (1.f + expf(-y1));
    if (u < 32) {
      float ss = y0 * y0 + y1 * y1;
      #pragma unroll
      for (int m = 1; m < 64; m <<= 1) ss += __shfl_xor(ss, m);
      float rs = rsqrtf(ss + 1e-6f);
      if (u < 16) rs *= 0.08838834764831845f;   // DK^-0.5
      y0 *= rs; y1 *= rs;
      _Float16* dst = (u < 16 ? qn : kn) + (size_t)row * 2048 + hh * 128;
      f16x2 o; o[0] = (_Float16)y0; o[1] = (_Float16)y1;
      *(f16x2*)(dst + 2 * lane) = o;
    } else {
      _Float16* dst = vb + (size_t)row * 4096 + hh * 128;
      f16x2 o; o[0] = (_Float16)y0; o[1] = (_Float16)y1;
      *(f16x2*)(dst + 2 * lane) = o;
    }
  }
}

// ---------------- g/beta from fp32 ba; outputs TRANSPOSED [vh][b*2048+t] ----------------
__global__ __launch_bounds__(256)
void egbeta_kernel(const float* __restrict__ ba, const float* __restrict__ Alog,
                   const float* __restrict__ dtb, float* __restrict__ gout,
                   float* __restrict__ bout) {
  int i = blockIdx.x * 256 + threadIdx.x;     // MROWS*32
  if (i >= MROWS * 32) return;
  int vh = i >> 12, row = i & 4095;
  int kh = vh >> 1, r = vh & 1;
  const float* p = ba + (size_t)row * 64 + kh * 4;
  float bv = p[r], av = p[2 + r];
  float x = av + dtb[vh];
  float sp = (x > 20.f) ? x : log1pf(expf(x));
  gout[(size_t)vh * MROWS + row] = -expf(Alog[vh]) * sp;
  bout[(size_t)vh * MROWS + row] = 1.f / (1.f + expf(-bv));
}

// ---------------- chunked gated delta-rule scan (UT transform, MFMA, 8 waves) ----------------
__global__ __launch_bounds__(512, 2)
void chunk_scan(const _Float16* __restrict__ qn, const _Float16* __restrict__ kn,
                _Float16* __restrict__ vb, const float* __restrict__ gb,
                const float* __restrict__ btb) {
  __shared__ __align__(16) _Float16 Ks[64 * 128];   // [t][k] swz256
  __shared__ __align__(16) _Float16 Qs[64 * 128];   // [t][k] swz256
  __shared__ __align__(16) _Float16 Kt[128 * 64];   // [k][s] swz128
  __shared__ __align__(16) _Float16 Sf[32 * 128];   // [v][k] f16 state copy, swz256
  __shared__ float AT[64 * 65];                     // AT[s][t] = A[t][s]
  __shared__ __align__(16) _Float16 M16[64 * 64];   // [t][s] swz128
  __shared__ float RHS[32 * 65];                    // [v][t]
  __shared__ __align__(16) _Float16 Uv[32 * 64];    // [v][s] swz128 (raw u)
  __shared__ __align__(16) _Float16 Ub[32 * 64];    // [v][s] swz128 (u * scU[s])
  __shared__ __align__(16) _Float16 Vb[64 * 32];    // [t][v] linear, 64B rows
  __shared__ float gs[64], bs[64], cgs[64], bexp[64], scU[64];

  char* Ksb = (char*)Ks; char* Qsb = (char*)Qs; char* Ktb = (char*)Kt;
  char* Sfb = (char*)Sf; char* M16b = (char*)M16;
  char* Uvb = (char*)Uv; char* Ubb = (char*)Ub; char* Vbb = (char*)Vb;

  int bid = blockIdx.x;
  int b = bid >> 7, vh = (bid >> 2) & 31, vsl = bid & 3;
  int kh = vh >> 1;
  int tid = threadIdx.x;
  int w = tid >> 6, lane = tid & 63;
  int wr = w >> 1, wc = w & 1;
  int la = lane & 15, lk = lane >> 4;

  const _Float16* kgb = kn + (size_t)(b * 2048) * 2048 + kh * 128;
  const _Float16* qgb = qn + (size_t)(b * 2048) * 2048 + kh * 128;
  _Float16*       vgb = vb + (size_t)(b * 2048) * 4096 + vh * 128 + vsl * 32;
  const float*    ggb = gb  + (size_t)vh * MROWS + b * 2048;
  const float*    bgb = btb + (size_t)vh * MROWS + b * 2048;

  int srow = tid >> 3, sseg = tid & 7;
  int tk = tid & 127, tth = tid >> 7;

  f16x8 kr[2], qr[2]; f16x4 vr; float ebr;
  float sreg[2][4] = {};                 // S[v = vt*16+lk*4+r][k = w*16+la]

  { f32x4 z = {}; ((f32x4*)Sf)[tid] = z; }

  kr[0] = *(const f16x8*)(kgb + (size_t)srow * 2048 + sseg * 16);
  kr[1] = *(const f16x8*)(kgb + (size_t)srow * 2048 + sseg * 16 + 8);
  qr[0] = *(const f16x8*)(qgb + (size_t)srow * 2048 + sseg * 16);
  qr[1] = *(const f16x8*)(qgb + (size_t)srow * 2048 + sseg * 16 + 8);
  vr    = *(const f16x4*)(vgb + (size_t)srow * 4096 + sseg * 4);
  ebr   = (tid < 64) ? ggb[tid] : (tid < 128 ? bgb[tid - 64] : 0.f);
  *(f16x8*)(Ksb + swz256(srow, sseg * 32))      = kr[0];
  *(f16x8*)(Ksb + swz256(srow, sseg * 32 + 16)) = kr[1];
  *(f16x8*)(Qsb + swz256(srow, sseg * 32))      = qr[0];
  *(f16x8*)(Qsb + swz256(srow, sseg * 32 + 16)) = qr[1];
  *(f16x4*)(Vbb + srow * 64 + sseg * 8) = vr;
  if (tid < 64) gs[tid] = ebr; else if (tid < 128) bs[tid - 64] = ebr;
  __syncthreads();

  #pragma unroll 1
  for (int c = 0; c < NCHUNK; ++c) {
    int cn = (c < NCHUNK - 1) ? c + 1 : c;
    kr[0] = *(const f16x8*)(kgb + (size_t)(cn * 64 + srow) * 2048 + sseg * 16);
    kr[1] = *(const f16x8*)(kgb + (size_t)(cn * 64 + srow) * 2048 + sseg * 16 + 8);
    qr[0] = *(const f16x8*)(qgb + (size_t)(cn * 64 + srow) * 2048 + sseg * 16);
    qr[1] = *(const f16x8*)(qgb + (size_t)(cn * 64 + srow) * 2048 + sseg * 16 + 8);
    vr    = *(const f16x4*)(vgb + (size_t)(cn * 64 + srow) * 4096 + sseg * 4);
    ebr   = (tid < 64) ? ggb[cn * 64 + tid] : (tid < 128 ? bgb[cn * 64 + tid - 64] : 0.f);

    f32x4 kk[2] = {}, qk[2] = {}, ks0 = {}, qs0 = {};
    #pragma unroll
    for (int ks = 0; ks < 4; ++ks) {
      f16x8 aK = *(const f16x8*)(Ksb + swz256(wr * 16 + la, ks * 64 + lk * 16));
      f16x8 aQ = *(const f16x8*)(Qsb + swz256(wr * 16 + la, ks * 64 + lk * 16));
      f16x8 bS = *(const f16x8*)(Sfb + swz256(wc * 16 + la, ks * 64 + lk * 16));
      #pragma unroll
      for (int j = 0; j < 2; ++j) {
        f16x8 bK = *(const f16x8*)(Ksb + swz256(wc * 32 + j * 16 + la, ks * 64 + lk * 16));
        kk[j] = __builtin_amdgcn_mfma_f32_16x16x32_f16(aK, bK, kk[j], 0, 0, 0);
        qk[j] = __builtin_amdgcn_mfma_f32_16x16x32_f16(aQ, bK, qk[j], 0, 0, 0);
      }
      ks0 = __builtin_amdgcn_mfma_f32_16x16x32_f16(aK, bS, ks0, 0, 0, 0);
      qs0 = __builtin_amdgcn_mfma_f32_16x16x32_f16(aQ, bS, qs0, 0, 0, 0);
    }
    {
      f16x8 r0, r1;
      #pragma unroll
      for (int j = 0; j < 8; ++j) {
        r0[j] = *(const _Float16*)(Ksb + swz256(tth * 16 + j, 2 * tk));
        r1[j] = *(const _Float16*)(Ksb + swz256(tth * 16 + 8 + j, 2 * tk));
      }
      *(f16x8*)(Ktb + swz128(tk, tth * 32))      = r0;
      *(f16x8*)(Ktb + swz128(tk, tth * 32 + 16)) = r1;
    }
    if (w == 0) {
      float g = gs[lane];
      #pragma unroll
      for (int off = 1; off < 64; off <<= 1) {
        float y = __shfl_up(g, off);
        if (lane >= off) g += y;
      }
      cgs[lane] = g;
      float cgL = __shfl(g, 63);
      bexp[lane] = __expf(g);
      scU[lane] = bs[lane] * __expf(cgL - g);
    }
    __syncthreads();   // B1

    {
      float cgt[4];
      #pragma unroll
      for (int r = 0; r < 4; ++r) cgt[r] = cgs[wr * 16 + lk * 4 + r];
      #pragma unroll
      for (int j = 0; j < 2; ++j) {
        int s = wc * 32 + j * 16 + la;
        float bsv = bs[s], cgss = cgs[s];
        #pragma unroll
        for (int r = 0; r < 4; ++r) {
          int t = wr * 16 + lk * 4 + r;
          float e = bsv * __expf(cgt[r] - cgss);
          AT[s * 65 + t] = (s < t) ? e * kk[j][r] : 0.f;
          float mm = (s <= t) ? e * qk[j][r] : 0.f;
          *(_Float16*)(M16b + swz128(t, s * 2)) = (_Float16)mm;
        }
      }
      #pragma unroll
      for (int r = 0; r < 4; ++r) {
        int t = wr * 16 + lk * 4 + r;
        int v = wc * 16 + la;
        float be = bexp[t];
        qs0[r] *= be;
        float vv = (float)*(const _Float16*)(Vbb + t * 64 + v * 2);
        RHS[v * 65 + t] = vv - be * ks0[r];
      }
    }
    __syncthreads();   // B2

    {
      float u[4];
      #pragma unroll
      for (int vi = 0; vi < 4; ++vi) u[vi] = RHS[(w * 4 + vi) * 65 + lane];
      #pragma unroll 1
      for (int sb = 0; sb < 8; ++sb) {
        float Ac[8];
        #pragma unroll
        for (int j = 0; j < 8; ++j) Ac[j] = AT[(sb * 8 + j) * 65 + lane];
        #pragma unroll
        for (int j = 0; j < 8; ++j) {
          int s = sb * 8 + j;
          #pragma unroll
          for (int vi = 0; vi < 4; ++vi) {
            float ubv = __builtin_bit_cast(float,
                __builtin_amdgcn_readlane(__builtin_bit_cast(int, u[vi]), s));
            u[vi] = fmaf(-Ac[j], ubv, u[vi]);
          }
        }
      }
      float sc = scU[lane];
      #pragma unroll
      for (int vi = 0; vi < 4; ++vi) {
        int v = w * 4 + vi;
        *(_Float16*)(Uvb + swz128(v, lane * 2)) = (_Float16)u[vi];
        *(_Float16*)(Ubb + swz128(v, lane * 2)) = (_Float16)(u[vi] * sc);
      }
    }
    __syncthreads();   // B3

    #pragma unroll
    for (int ss = 0; ss < 2; ++ss) {
      f16x8 aM = *(const f16x8*)(M16b + swz128(wr * 16 + la, ss * 64 + lk * 16));
      f16x8 bU = *(const f16x8*)(Uvb + swz128(wc * 16 + la, ss * 64 + lk * 16));
      qs0 = __builtin_amdgcn_mfma_f32_16x16x32_f16(aM, bU, qs0, 0, 0, 0);
    }
    #pragma unroll
    for (int r = 0; r < 4; ++r) {
      int t = wr * 16 + lk * 4 + r;
      vgb[(size_t)(c * 64 + t) * 4096 + wc * 16 + la] = (_Float16)qs0[r];  // in-place: v[t] dead
    }
    {
      f32x4 sd[2] = {};
      #pragma unroll
      for (int ss = 0; ss < 2; ++ss) {
        f16x8 bK = *(const f16x8*)(Ktb + swz128(w * 16 + la, ss * 64 + lk * 16));
        #pragma unroll
        for (int vt = 0; vt < 2; ++vt) {
          f16x8 aU = *(const f16x8*)(Ubb + swz128(vt * 16 + la, ss * 64 + lk * 16));
          sd[vt] = __builtin_amdgcn_mfma_f32_16x16x32_f16(aU, bK, sd[vt], 0, 0, 0);
        }
      }
      float beC = bexp[63];
      #pragma unroll
      for (int vt = 0; vt < 2; ++vt)
        #pragma unroll
        for (int r = 0; r < 4; ++r) {
          int v = vt * 16 + lk * 4 + r;
          int k = w * 16 + la;
          float sn = fmaf(sreg[vt][r], beC, sd[vt][r]);
          sreg[vt][r] = sn;
          *(_Float16*)(Sfb + swz256(v, k * 2)) = (_Float16)sn;
        }
    }
    __syncthreads();   // B4

    *(f16x8*)(Ksb + swz256(srow, sseg * 32))      = kr[0];
    *(f16x8*)(Ksb + swz256(srow, sseg * 32 + 16)) = kr[1];
    *(f16x8*)(Qsb + swz256(srow, sseg * 32))      = qr[0];
    *(f16x8*)(Qsb + swz256(srow, sseg * 32 + 16)) = qr[1];
    *(f16x4*)(Vbb + srow * 64 + sseg * 8) = vr;
    if (tid < 64) gs[tid] = ebr; else if (tid < 128) bs[tid - 64] = ebr;
    __syncthreads();   // B5
  }
}

// ---------------- RMSNorm * norm_kernel * silu(z) -> fp16 Ag ----------------
__global__ __launch_bounds__(256)
void gate_kernel(const _Float16* __restrict__ ob, const _Float16* __restrict__ qkvz,
                 const float* __restrict__ nk, _Float16* __restrict__ Ag) {
  int row = blockIdx.x;
  int lane = threadIdx.x & 63, wid = threadIdx.x >> 6;
  for (int vh = wid; vh < 32; vh += 4) {
    const _Float16* op = ob + (size_t)row * 4096 + vh * 128;
    f16x2 xx = *(const f16x2*)(op + 2 * lane);
    float x0 = (float)xx[0], x1 = (float)xx[1];
    float ss = x0 * x0 + x1 * x1;
    #pragma unroll
    for (int m = 1; m < 64; m <<= 1) ss += __shfl_xor(ss, m);
    float rs = rsqrtf(ss * (1.f / 128.f) + 1e-6f);
    f32x2 nv = *(const f32x2*)(nk + 2 * lane);
    float v0 = x0 * rs * nv[0], v1 = x1 * rs * nv[1];
    const _Float16* zp = qkvz + (size_t)row * NQKV + (vh >> 1) * 768 + 512 + (vh & 1) * 128;
    f16x2 zz = *(const f16x2*)(zp + 2 * lane);
    float z0 = (float)zz[0], z1 = (float)zz[1];
    v0 *= z0 / (1.f + expf(-z0));
    v1 *= z1 / (1.f + expf(-z1));
    _Float16* dst = Ag + (size_t)row * 4096 + vh * 128;
    f16x2 o; o[0] = (_Float16)v0; o[1] = (_Float16)v1;
    *(f16x2*)(dst + 2 * lane) = o;
  }
}

extern "C" void kernel_launch(void* const* d_in, const int* in_sizes, int n_in,
                              void* d_out, int out_size, void* d_ws, size_t ws_size,
                              hipStream_t stream) {
  const float* h     = (const float*)d_in[0];
  const float* mask  = (const float*)d_in[1];
  const float* Wqkvz = (const float*)d_in[2];
  const float* Wba   = (const float*)d_in[3];
  const float* ck    = (const float*)d_in[4];
  const float* Alog  = (const float*)d_in[5];
  const float* dtb   = (const float*)d_in[6];
  const float* nk    = (const float*)d_in[7];
  const float* Wout  = (const float*)d_in[8];
  float* out = (float*)d_out;

  char* w = (char*)d_ws;
  const size_t o_qkvz = 0;                         // 100,663,296  [gemm1 .. gate]
  const size_t o_A1   = 100663296;                 //  16,777,216  [amask .. gemm1]
  const size_t o_Bt1  = o_A1 + 16777216;           //  50,331,648  [transpose .. gemm1]
  const size_t o_ba   = o_Bt1 + 50331648;          //   1,048,576
  const size_t o_g    = o_ba + 1048576;            //     524,288
  const size_t o_bt   = o_g + 524288;              //     524,288
  const size_t total  = o_bt + 524288;             // 169,869,312 B = 162 MiB
  if (ws_size < total) return;

  _Float16* qkvz16 = (_Float16*)(w + o_qkvz);
  _Float16* A1     = (_Float16*)(w + o_A1);
  _Float16* Bt1    = (_Float16*)(w + o_Bt1);
  float*    ba32   = (float*)   (w + o_ba);
  float*    gbuf   = (float*)   (w + o_g);
  float*    btb    = (float*)   (w + o_bt);
  // aliases over dead regions:
  _Float16* qn16 = (_Float16*)(w + o_A1);                    // over A1 (dead after gemm1)
  _Float16* kn16 = (_Float16*)(w + o_Bt1);                   // over Bt1[0:16M)
  _Float16* vb16 = (_Float16*)(w + o_Bt1 + 16777216);        // over Bt1[16M:50M); o in-place
  _Float16* Ag   = (_Float16*)(w + o_A1);                    // over qn+kn (dead after scan)
  _Float16* Wt2  = (_Float16*)(w + 0);                       // over qkvz (dead after gate)

  amask_kernel<<<MROWS * HIDD / 4 / 256, 256, 0, stream>>>(h, mask, A1);
  transpose_f16<<<dim3(192, 32), 256, 0, stream>>>(Wqkvz, Bt1, HIDD, NQKV);
  ba_gemm<<<MROWS / 8, 256, 0, stream>>>(h, mask, Wba, ba32);
  gemm2ph<_Float16, 256><<<16 * 48, 512, 0, stream>>>(A1, Bt1, qkvz16, MROWS, NQKV, HIDD, 48);
  conv_kernel<<<MROWS, 256, 0, stream>>>(qkvz16, ck, qn16, kn16, vb16);
  egbeta_kernel<<<MROWS * 32 / 256, 256, 0, stream>>>(ba32, Alog, dtb, gbuf, btb);
  chunk_scan<<<256, 512, 0, stream>>>(qn16, kn16, vb16, gbuf, btb);
  gate_kernel<<<MROWS, 256, 0, stream>>>(vb16, qkvz16, nk, Ag);
  transpose_f16<<<dim3(32, 64), 256, 0, stream>>>(Wout, Wt2, 4096, HIDD);
  gemm2ph<float, 128><<<32 * 8, 512, 0, stream>>>(Ag, Wt2, out, MROWS, HIDD, 4096, 8);
}

// Round 8
// 693.597 us; speedup vs baseline: 2.6145x; 1.0095x over previous
//
#include <hip/hip_runtime.h>
#include <stdint.h>

typedef float    f32x4 __attribute__((ext_vector_type(4)));
typedef float    f32x2 __attribute__((ext_vector_type(2)));
typedef _Float16 f16x8 __attribute__((ext_vector_type(8)));
typedef _Float16 f16x4 __attribute__((ext_vector_type(4)));
typedef _Float16 f16x2 __attribute__((ext_vector_type(2)));

#define SEQ   2048
#define HIDD  2048
#define MROWS 4096
#define NQKV  12288          // 96 x 128, no pad
#define NCHUNK 32
#define CLEN   64

__device__ __forceinline__ void gload_lds16(const void* g, void* l) {
  __builtin_amdgcn_global_load_lds((const __attribute__((address_space(1))) uint32_t*)g,
                                   (__attribute__((address_space(3))) uint32_t*)l, 16, 0, 0);
}
// XOR swizzles (byte addressing) for bank-conflict-free f16 frag reads
__device__ __forceinline__ int swz256(int row, int colb) { return row * 256 + (colb ^ ((row & 7) << 4)); }
__device__ __forceinline__ int swz128(int row, int colb) { return row * 128 + (colb ^ ((row & 7) << 4)); }

// ---------------- A = (h * mask) -> fp16 ----------------
__global__ __launch_bounds__(256)
void amask_kernel(const float* __restrict__ h, const float* __restrict__ mask,
                  _Float16* __restrict__ A1) {
  int i = blockIdx.x * 256 + threadIdx.x;            // one float4 each
  if (i >= MROWS * HIDD / 4) return;
  f32x4 x = ((const f32x4*)h)[i];
  float m = mask[(i * 4) >> 11];
  f16x4 r;
  r[0] = (_Float16)(x[0] * m); r[1] = (_Float16)(x[1] * m);
  r[2] = (_Float16)(x[2] * m); r[3] = (_Float16)(x[3] * m);
  *(f16x4*)(A1 + (size_t)i * 4) = r;
}

// ---------------- transpose fp32 [R][C] -> fp16 [C][R] ----------------
__global__ __launch_bounds__(256)
void transpose_f16(const float* __restrict__ in, _Float16* __restrict__ out,
                   int R, int C) {
  __shared__ float tile[64][65];
  int c0 = blockIdx.x * 64, r0 = blockIdx.y * 64;
  int tx = threadIdx.x & 63, ty = threadIdx.x >> 6;
  #pragma unroll
  for (int i = 0; i < 16; ++i) {
    int r = i * 4 + ty;
    tile[r][tx] = in[(size_t)(r0 + r) * C + c0 + tx];
  }
  __syncthreads();
  #pragma unroll
  for (int i = 0; i < 16; ++i) {
    int c = i * 4 + ty;
    out[(size_t)(c0 + c) * R + r0 + tx] = (_Float16)tile[tx][c];
  }
}

// ---------------- BMx256 / BK=64 / 8-wave fp16 MFMA GEMM, 8-phase schedule ----------------
// C[M][N] = A[M][K] * Bt[N][K]^T.  Per K-tile: tile-top {vmcnt(0); s_barrier} validates
// buf[cur] (its loads were issued a full tile earlier); then 4 phases = C-quadrants,
// each a setprio-wrapped MFMA cluster between RAW s_barriers (no vmcnt drain).
// Reads: all bf + half the af in P(0,0), af refill at P(1,0) -> 24 b128/K-tile (no re-read).
// Staging for kt+1 -> buf^1 issued in P0 (in flight >= 3 phases). T2 swizzle via
// pre-swizzled global source column (LDS dest linear, read side applies same XOR).
template <typename CT, int BM>
__global__ __launch_bounds__(512, 2)
void gemm8p(const _Float16* __restrict__ A, const _Float16* __restrict__ Bt,
            CT* __restrict__ C, int M, int N, int K, int tiles_n) {
  constexpr int RF  = BM / 32;          // row frags per wave (8 or 4)
  constexpr int RH  = RF / 2;           // frags per pm-half
  constexpr int AR  = BM / 8;           // A rows staged per wave
  constexpr int NA  = AR / 8;           // A stage insts per thread
  __shared__ __align__(16) _Float16 lsA[2][BM * 64];
  __shared__ __align__(16) _Float16 lsB[2][256 * 64];
  int bm = blockIdx.x / tiles_n, bn = blockIdx.x % tiles_n;
  int m0 = bm * BM, n0 = bn * 256;
  int tid = threadIdx.x;
  int w = tid >> 6, lane = tid & 63;
  int wm = w >> 2, wn = w & 3;          // wave tile: rows [wm*(BM/2),+BM/2), cols [wn*64,+64)
  int la = lane & 15, lk = lane >> 4;
  int sr = lane >> 3;                               // slab row 0..7
  int scb = ((lane & 7) << 4) ^ ((sr & 7) << 4);    // pre-swizzled source byte col
  int nkt = K >> 6;
  f32x4 acc[RF][4] = {};

  auto stage = [&](int kt, int buf) {
    const char* ga = (const char*)(A  + (size_t)(m0 + w * AR) * K + kt * 64);
    const char* gb = (const char*)(Bt + (size_t)(n0 + w * 32) * K + kt * 64);
    #pragma unroll
    for (int i = 0; i < NA; ++i)
      gload_lds16(ga + (size_t)(i * 8 + sr) * (K * 2) + scb, &lsA[buf][(w * AR + i * 8) * 64]);
    #pragma unroll
    for (int i = 0; i < 4; ++i)
      gload_lds16(gb + (size_t)(i * 8 + sr) * (K * 2) + scb, &lsB[buf][(w * 32 + i * 8) * 64]);
  };

  stage(0, 0);

  int cur = 0;
  for (int kt = 0; kt < nkt; ++kt) {
    asm volatile("s_waitcnt vmcnt(0)" ::: "memory");   // buf[cur] loads landed (issued 1 tile ago)
    __builtin_amdgcn_s_barrier();                      // all waves' loads done
    __builtin_amdgcn_sched_barrier(0);
    const char* cA = (const char*)&lsA[cur][0];
    const char* cB = (const char*)&lsB[cur][0];
    f16x8 bf[4][2], af[RH][2];
    // ---- P(0,0): read all bf + af half 0; issue staging; MFMA quadrant (0, cols 0-1)
    #pragma unroll
    for (int j = 0; j < 4; ++j)
      #pragma unroll
      for (int kw = 0; kw < 2; ++kw) {
        int row = wn * 64 + j * 16 + la;
        bf[j][kw] = *(const f16x8*)(cB + row * 128 + ((kw * 64 + lk * 16) ^ ((row & 7) << 4)));
      }
    #pragma unroll
    for (int r = 0; r < RH; ++r)
      #pragma unroll
      for (int kw = 0; kw < 2; ++kw) {
        int row = wm * (BM / 2) + r * 16 + la;
        af[r][kw] = *(const f16x8*)(cA + row * 128 + ((kw * 64 + lk * 16) ^ ((row & 7) << 4)));
      }
    if (kt + 1 < nkt) stage(kt + 1, cur ^ 1);
    __builtin_amdgcn_s_barrier();
    __builtin_amdgcn_sched_barrier(0);
    __builtin_amdgcn_s_setprio(1);
    #pragma unroll
    for (int r = 0; r < RH; ++r)
      #pragma unroll
      for (int j = 0; j < 2; ++j)
        #pragma unroll
        for (int kw = 0; kw < 2; ++kw)
          acc[r][j] = __builtin_amdgcn_mfma_f32_16x16x32_f16(af[r][kw], bf[j][kw], acc[r][j], 0, 0, 0);
    __builtin_amdgcn_s_setprio(0);
    __builtin_amdgcn_s_barrier();
    __builtin_amdgcn_sched_barrier(0);
    // ---- P(0,1): cols 2-3
    __builtin_amdgcn_s_setprio(1);
    #pragma unroll
    for (int r = 0; r < RH; ++r)
      #pragma unroll
      for (int j = 2; j < 4; ++j)
        #pragma unroll
        for (int kw = 0; kw < 2; ++kw)
          acc[r][j] = __builtin_amdgcn_mfma_f32_16x16x32_f16(af[r][kw], bf[j][kw], acc[r][j], 0, 0, 0);
    __builtin_amdgcn_s_setprio(0);
    __builtin_amdgcn_s_barrier();
    __builtin_amdgcn_sched_barrier(0);
    // ---- P(1,0): refill af with half 1; cols 0-1
    #pragma unroll
    for (int r = 0; r < RH; ++r)
      #pragma unroll
      for (int kw = 0; kw < 2; ++kw) {
        int row = wm * (BM / 2) + (RH + r) * 16 + la;
        af[r][kw] = *(const f16x8*)(cA + row * 128 + ((kw * 64 + lk * 16) ^ ((row & 7) << 4)));
      }
    __builtin_amdgcn_s_barrier();
    __builtin_amdgcn_sched_barrier(0);
    __builtin_amdgcn_s_setprio(1);
    #pragma unroll
    for (int r = 0; r < RH; ++r)
      #pragma unroll
      for (int j = 0; j < 2; ++j)
        #pragma unroll
        for (int kw = 0; kw < 2; ++kw)
          acc[RH + r][j] = __builtin_amdgcn_mfma_f32_16x16x32_f16(af[r][kw], bf[j][kw], acc[RH + r][j], 0, 0, 0);
    __builtin_amdgcn_s_setprio(0);
    __builtin_amdgcn_s_barrier();
    __builtin_amdgcn_sched_barrier(0);
    // ---- P(1,1): cols 2-3
    __builtin_amdgcn_s_setprio(1);
    #pragma unroll
    for (int r = 0; r < RH; ++r)
      #pragma unroll
      for (int j = 2; j < 4; ++j)
        #pragma unroll
        for (int kw = 0; kw < 2; ++kw)
          acc[RH + r][j] = __builtin_amdgcn_mfma_f32_16x16x32_f16(af[r][kw], bf[j][kw], acc[RH + r][j], 0, 0, 0);
    __builtin_amdgcn_s_setprio(0);
    __builtin_amdgcn_s_barrier();
    __builtin_amdgcn_sched_barrier(0);
    cur ^= 1;
  }

  #pragma unroll
  for (int f = 0; f < RF; ++f)
    #pragma unroll
    for (int j = 0; j < 4; ++j) {
      int col = n0 + wn * 64 + j * 16 + la;
      #pragma unroll
      for (int r = 0; r < 4; ++r) {
        int row = m0 + wm * (BM / 2) + f * 16 + lk * 4 + r;
        C[(size_t)row * N + col] = (CT)acc[f][j][r];
      }
    }
}

// ---------------- ba = (h*mask) @ W_ba in fp32 (precision-critical for g) ----------------
__global__ __launch_bounds__(256)
void ba_gemm(const float* __restrict__ h, const float* __restrict__ mask,
             const float* __restrict__ Wba, float* __restrict__ ba) {
  __shared__ float red[4][8][64];
  int r0 = blockIdx.x * 8;
  int c = threadIdx.x & 63, kc = threadIdx.x >> 6;
  float acc[8] = {};
  const float* wp = Wba + (size_t)(kc * 512) * 64 + c;
  const float* hp = h + (size_t)r0 * HIDD + kc * 512;
  for (int i = 0; i < 512; ++i) {
    float w = wp[(size_t)i * 64];
    #pragma unroll
    for (int r = 0; r < 8; ++r)
      acc[r] += hp[(size_t)r * HIDD + i] * w;
  }
  #pragma unroll
  for (int r = 0; r < 8; ++r) red[kc][r][c] = acc[r];
  __syncthreads();
  if (kc == 0) {
    #pragma unroll
    for (int r = 0; r < 8; ++r) {
      float s = red[0][r][c] + red[1][r][c] + red[2][r][c] + red[3][r][c];
      ba[(size_t)(r0 + r) * 64 + c] = s * mask[r0 + r];
    }
  }
}

// ---------------- conv(4-tap causal) + SiLU + l2norm -> qn16, kn16, vb16 ----------------
__global__ __launch_bounds__(256)
void conv_kernel(const _Float16* __restrict__ qkvz, const float* __restrict__ ck,
                 _Float16* __restrict__ qn, _Float16* __restrict__ kn,
                 _Float16* __restrict__ vb) {
  int row = blockIdx.x;               // b*2048 + t
  int b = row >> 11, t = row & 2047;
  int lane = threadIdx.x & 63, wid = threadIdx.x >> 6;
  for (int u = wid; u < 64; u += 4) {
    int c, cc, hh;
    if (u < 16)      { hh = u;      c = hh * 768;                               cc = hh * 128; }
    else if (u < 32) { hh = u - 16; c = hh * 768 + 128;                         cc = 2048 + hh * 128; }
    else             { hh = u - 32; c = (hh >> 1) * 768 + 256 + (hh & 1) * 128; cc = 4096 + hh * 128; }
    float y0 = 0.f, y1 = 0.f;
    #pragma unroll
    for (int j = 0; j < 4; ++j) {
      int tt = t - 3 + j;
      if (tt >= 0) {
        const _Float16* r = qkvz + (size_t)(b * 2048 + tt) * NQKV + c;
        f16x2 x = *(const f16x2*)(r + 2 * lane);
        f32x2 w = *(const f32x2*)(ck + j * 8192 + cc + 2 * lane);
        y0 += (float)x[0] * w[0];
        y1 += (float)x[1] * w[1];
      }
    }
    y0 = y0 / (1.f + expf(-y0));
    y1 = y1 / (1.f + expf(-y1));
    if (u < 32) {
      float ss = y0 * y0 + y1 * y1;
      #pragma unroll
      for (int m = 1; m < 64; m <<= 1) ss += __shfl_xor(ss, m);
      float rs = rsqrtf(ss + 1e-6f);
      if (u < 16) rs *= 0.08838834764831845f;   // DK^-0.5
      y0 *= rs; y1 *= rs;
      _Float16* dst = (u < 16 ? qn : kn) + (size_t)row * 2048 + hh * 128;
      f16x2 o; o[0] = (_Float16)y0; o[1] = (_Float16)y1;
      *(f16x2*)(dst + 2 * lane) = o;
    } else {
      _Float16* dst = vb + (size_t)row * 4096 + hh * 128;
      f16x2 o; o[0] = (_Float16)y0; o[1] = (_Float16)y1;
      *(f16x2*)(dst + 2 * lane) = o;
    }
  }
}

// ---------------- g/beta from fp32 ba; outputs TRANSPOSED [vh][b*2048+t] ----------------
__global__ __launch_bounds__(256)
void egbeta_kernel(const float* __restrict__ ba, const float* __restrict__ Alog,
                   const float* __restrict__ dtb, float* __restrict__ gout,
                   float* __restrict__ bout) {
  int i = blockIdx.x * 256 + threadIdx.x;     // MROWS*32
  if (i >= MROWS * 32) return;
  int vh = i >> 12, row = i & 4095;
  int kh = vh >> 1, r = vh & 1;
  const float* p = ba + (size_t)row * 64 + kh * 4;
  float bv = p[r], av = p[2 + r];
  float x = av + dtb[vh];
  float sp = (x > 20.f) ? x : log1pf(expf(x));
  gout[(size_t)vh * MROWS + row] = -expf(Alog[vh]) * sp;
  bout[(size_t)vh * MROWS + row] = 1.f / (1.f + expf(-bv));
}

// ---------------- chunked gated delta-rule scan (UT transform, MFMA, 8 waves) ----------------
__global__ __launch_bounds__(512, 2)
void chunk_scan(const _Float16* __restrict__ qn, const _Float16* __restrict__ kn,
                _Float16* __restrict__ vb, const float* __restrict__ gb,
                const float* __restrict__ btb) {
  __shared__ __align__(16) _Float16 Ks[64 * 128];   // [t][k] swz256
  __shared__ __align__(16) _Float16 Qs[64 * 128];   // [t][k] swz256
  __shared__ __align__(16) _Float16 Kt[128 * 64];   // [k][s] swz128
  __shared__ __align__(16) _Float16 Sf[32 * 128];   // [v][k] f16 state copy, swz256
  __shared__ float AT[64 * 65];                     // AT[s][t] = A[t][s]
  __shared__ __align__(16) _Float16 M16[64 * 64];   // [t][s] swz128
  __shared__ float RHS[32 * 65];                    // [v][t]
  __shared__ __align__(16) _Float16 Uv[32 * 64];    // [v][s] swz128 (raw u)
  __shared__ __align__(16) _Float16 Ub[32 * 64];    // [v][s] swz128 (u * scU[s])
  __shared__ __align__(16) _Float16 Vb[64 * 32];    // [t][v] linear, 64B rows
  __shared__ float gs[64], bs[64], cgs[64], bexp[64], scU[64];

  char* Ksb = (char*)Ks; char* Qsb = (char*)Qs; char* Ktb = (char*)Kt;
  char* Sfb = (char*)Sf; char* M16b = (char*)M16;
  char* Uvb = (char*)Uv; char* Ubb = (char*)Ub; char* Vbb = (char*)Vb;

  int bid = blockIdx.x;
  int b = bid >> 7, vh = (bid >> 2) & 31, vsl = bid & 3;
  int kh = vh >> 1;
  int tid = threadIdx.x;
  int w = tid >> 6, lane = tid & 63;
  int wr = w >> 1, wc = w & 1;
  int la = lane & 15, lk = lane >> 4;

  const _Float16* kgb = kn + (size_t)(b * 2048) * 2048 + kh * 128;
  const _Float16* qgb = qn + (size_t)(b * 2048) * 2048 + kh * 128;
  _Float16*       vgb = vb + (size_t)(b * 2048) * 4096 + vh * 128 + vsl * 32;
  const float*    ggb = gb  + (size_t)vh * MROWS + b * 2048;
  const float*    bgb = btb + (size_t)vh * MROWS + b * 2048;

  int srow = tid >> 3, sseg = tid & 7;
  int tk = tid & 127, tth = tid >> 7;

  f16x8 kr[2], qr[2]; f16x4 vr; float ebr;
  float sreg[2][4] = {};                 // S[v = vt*16+lk*4+r][k = w*16+la]

  { f32x4 z = {}; ((f32x4*)Sf)[tid] = z; }

  kr[0] = *(const f16x8*)(kgb + (size_t)srow * 2048 + sseg * 16);
  kr[1] = *(const f16x8*)(kgb + (size_t)srow * 2048 + sseg * 16 + 8);
  qr[0] = *(const f16x8*)(qgb + (size_t)srow * 2048 + sseg * 16);
  qr[1] = *(const f16x8*)(qgb + (size_t)srow * 2048 + sseg * 16 + 8);
  vr    = *(const f16x4*)(vgb + (size_t)srow * 4096 + sseg * 4);
  ebr   = (tid < 64) ? ggb[tid] : (tid < 128 ? bgb[tid - 64] : 0.f);
  *(f16x8*)(Ksb + swz256(srow, sseg * 32))      = kr[0];
  *(f16x8*)(Ksb + swz256(srow, sseg * 32 + 16)) = kr[1];
  *(f16x8*)(Qsb + swz256(srow, sseg * 32))      = qr[0];
  *(f16x8*)(Qsb + swz256(srow, sseg * 32 + 16)) = qr[1];
  *(f16x4*)(Vbb + srow * 64 + sseg * 8) = vr;
  if (tid < 64) gs[tid] = ebr; else if (tid < 128) bs[tid - 64] = ebr;
  __syncthreads();

  #pragma unroll 1
  for (int c = 0; c < NCHUNK; ++c) {
    int cn = (c < NCHUNK - 1) ? c + 1 : c;
    kr[0] = *(const f16x8*)(kgb + (size_t)(cn * 64 + srow) * 2048 + sseg * 16);
    kr[1] = *(const f16x8*)(kgb + (size_t)(cn * 64 + srow) * 2048 + sseg * 16 + 8);
    qr[0] = *(const f16x8*)(qgb + (size_t)(cn * 64 + srow) * 2048 + sseg * 16);
    qr[1] = *(const f16x8*)(qgb + (size_t)(cn * 64 + srow) * 2048 + sseg * 16 + 8);
    vr    = *(const f16x4*)(vgb + (size_t)(cn * 64 + srow) * 4096 + sseg * 4);
    ebr   = (tid < 64) ? ggb[cn * 64 + tid] : (tid < 128 ? bgb[cn * 64 + tid - 64] : 0.f);

    f32x4 kk[2] = {}, qk[2] = {}, ks0 = {}, qs0 = {};
    #pragma unroll
    for (int ks = 0; ks < 4; ++ks) {
      f16x8 aK = *(const f16x8*)(Ksb + swz256(wr * 16 + la, ks * 64 + lk * 16));
      f16x8 aQ = *(const f16x8*)(Qsb + swz256(wr * 16 + la, ks * 64 + lk * 16));
      f16x8 bS = *(const f16x8*)(Sfb + swz256(wc * 16 + la, ks * 64 + lk * 16));
      #pragma unroll
      for (int j = 0; j < 2; ++j) {
        f16x8 bK = *(const f16x8*)(Ksb + swz256(wc * 32 + j * 16 + la, ks * 64 + lk * 16));
        kk[j] = __builtin_amdgcn_mfma_f32_16x16x32_f16(aK, bK, kk[j], 0, 0, 0);
        qk[j] = __builtin_amdgcn_mfma_f32_16x16x32_f16(aQ, bK, qk[j], 0, 0, 0);
      }
      ks0 = __builtin_amdgcn_mfma_f32_16x16x32_f16(aK, bS, ks0, 0, 0, 0);
      qs0 = __builtin_amdgcn_mfma_f32_16x16x32_f16(aQ, bS, qs0, 0, 0, 0);
    }
    {
      f16x8 r0, r1;
      #pragma unroll
      for (int j = 0; j < 8; ++j) {
        r0[j] = *(const _Float16*)(Ksb + swz256(tth * 16 + j, 2 * tk));
        r1[j] = *(const _Float16*)(Ksb + swz256(tth * 16 + 8 + j, 2 * tk));
      }
      *(f16x8*)(Ktb + swz128(tk, tth * 32))      = r0;
      *(f16x8*)(Ktb + swz128(tk, tth * 32 + 16)) = r1;
    }
    if (w == 0) {
      float g = gs[lane];
      #pragma unroll
      for (int off = 1; off < 64; off <<= 1) {
        float y = __shfl_up(g, off);
        if (lane >= off) g += y;
      }
      cgs[lane] = g;
      float cgL = __shfl(g, 63);
      bexp[lane] = __expf(g);
      scU[lane] = bs[lane] * __expf(cgL - g);
    }
    __syncthreads();   // B1

    {
      float cgt[4];
      #pragma unroll
      for (int r = 0; r < 4; ++r) cgt[r] = cgs[wr * 16 + lk * 4 + r];
      #pragma unroll
      for (int j = 0; j < 2; ++j) {
        int s = wc * 32 + j * 16 + la;
        float bsv = bs[s], cgss = cgs[s];
        #pragma unroll
        for (int r = 0; r < 4; ++r) {
          int t = wr * 16 + lk * 4 + r;
          float e = bsv * __expf(cgt[r] - cgss);
          AT[s * 65 + t] = (s < t) ? e * kk[j][r] : 0.f;
          float mm = (s <= t) ? e * qk[j][r] : 0.f;
          *(_Float16*)(M16b + swz128(t, s * 2)) = (_Float16)mm;
        }
      }
      #pragma unroll
      for (int r = 0; r < 4; ++r) {
        int t = wr * 16 + lk * 4 + r;
        int v = wc * 16 + la;
        float be = bexp[t];
        qs0[r] *= be;
        float vv = (float)*(const _Float16*)(Vbb + t * 64 + v * 2);
        RHS[v * 65 + t] = vv - be * ks0[r];
      }
    }
    __syncthreads();   // B2

    {
      float u[4];
      #pragma unroll
      for (int vi = 0; vi < 4; ++vi) u[vi] = RHS[(w * 4 + vi) * 65 + lane];
      #pragma unroll 1
      for (int sb = 0; sb < 8; ++sb) {
        float Ac[8];
        #pragma unroll
        for (int j = 0; j < 8; ++j) Ac[j] = AT[(sb * 8 + j) * 65 + lane];
        #pragma unroll
        for (int j = 0; j < 8; ++j) {
          int s = sb * 8 + j;
          #pragma unroll
          for (int vi = 0; vi < 4; ++vi) {
            float ubv = __builtin_bit_cast(float,
                __builtin_amdgcn_readlane(__builtin_bit_cast(int, u[vi]), s));
            u[vi] = fmaf(-Ac[j], ubv, u[vi]);
          }
        }
      }
      float sc = scU[lane];
      #pragma unroll
      for (int vi = 0; vi < 4; ++vi) {
        int v = w * 4 + vi;
        *(_Float16*)(Uvb + swz128(v, lane * 2)) = (_Float16)u[vi];
        *(_Float16*)(Ubb + swz128(v, lane * 2)) = (_Float16)(u[vi] * sc);
      }
    }
    __syncthreads();   // B3

    #pragma unroll
    for (int ss = 0; ss < 2; ++ss) {
      f16x8 aM = *(const f16x8*)(M16b + swz128(wr * 16 + la, ss * 64 + lk * 16));
      f16x8 bU = *(const f16x8*)(Uvb + swz128(wc * 16 + la, ss * 64 + lk * 16));
      qs0 = __builtin_amdgcn_mfma_f32_16x16x32_f16(aM, bU, qs0, 0, 0, 0);
    }
    #pragma unroll
    for (int r = 0; r < 4; ++r) {
      int t = wr * 16 + lk * 4 + r;
      vgb[(size_t)(c * 64 + t) * 4096 + wc * 16 + la] = (_Float16)qs0[r];  // in-place: v[t] dead
    }
    {
      f32x4 sd[2] = {};
      #pragma unroll
      for (int ss = 0; ss < 2; ++ss) {
        f16x8 bK = *(const f16x8*)(Ktb + swz128(w * 16 + la, ss * 64 + lk * 16));
        #pragma unroll
        for (int vt = 0; vt < 2; ++vt) {
          f16x8 aU = *(const f16x8*)(Ubb + swz128(vt * 16 + la, ss * 64 + lk * 16));
          sd[vt] = __builtin_amdgcn_mfma_f32_16x16x32_f16(aU, bK, sd[vt], 0, 0, 0);
        }
      }
      float beC = bexp[63];
      #pragma unroll
      for (int vt = 0; vt < 2; ++vt)
        #pragma unroll
        for (int r = 0; r < 4; ++r) {
          int v = vt * 16 + lk * 4 + r;
          int k = w * 16 + la;
          float sn = fmaf(sreg[vt][r], beC, sd[vt][r]);
          sreg[vt][r] = sn;
          *(_Float16*)(Sfb + swz256(v, k * 2)) = (_Float16)sn;
        }
    }
    __syncthreads();   // B4

    *(f16x8*)(Ksb + swz256(srow, sseg * 32))      = kr[0];
    *(f16x8*)(Ksb + swz256(srow, sseg * 32 + 16)) = kr[1];
    *(f16x8*)(Qsb + swz256(srow, sseg * 32))      = qr[0];
    *(f16x8*)(Qsb + swz256(srow, sseg * 32 + 16)) = qr[1];
    *(f16x4*)(Vbb + srow * 64 + sseg * 8) = vr;
    if (tid < 64) gs[tid] = ebr; else if (tid < 128) bs[tid - 64] = ebr;
    __syncthreads();   // B5
  }
}

// ---------------- RMSNorm * norm_kernel * silu(z) -> fp16 Ag ----------------
__global__ __launch_bounds__(256)
void gate_kernel(const _Float16* __restrict__ ob, const _Float16* __restrict__ qkvz,
                 const float* __restrict__ nk, _Float16* __restrict__ Ag) {
  int row = blockIdx.x;
  int lane = threadIdx.x & 63, wid = threadIdx.x >> 6;
  for (int vh = wid; vh < 32; vh += 4) {
    const _Float16* op = ob + (size_t)row * 4096 + vh * 128;
    f16x2 xx = *(const f16x2*)(op + 2 * lane);
    float x0 = (float)xx[0], x1 = (float)xx[1];
    float ss = x0 * x0 + x1 * x1;
    #pragma unroll
    for (int m = 1; m < 64; m <<= 1) ss += __shfl_xor(ss, m);
    float rs = rsqrtf(ss * (1.f / 128.f) + 1e-6f);
    f32x2 nv = *(const f32x2*)(nk + 2 * lane);
    float v0 = x0 * rs * nv[0], v1 = x1 * rs * nv[1];
    const _Float16* zp = qkvz + (size_t)row * NQKV + (vh >> 1) * 768 + 512 + (vh & 1) * 128;
    f16x2 zz = *(const f16x2*)(zp + 2 * lane);
    float z0 = (float)zz[0], z1 = (float)zz[1];
    v0 *= z0 / (1.f + expf(-z0));
    v1 *= z1 / (1.f + expf(-z1));
    _Float16* dst = Ag + (size_t)row * 4096 + vh * 128;
    f16x2 o; o[0] = (_Float16)v0; o[1] = (_Float16)v1;
    *(f16x2*)(dst + 2 * lane) = o;
  }
}

extern "C" void kernel_launch(void* const* d_in, const int* in_sizes, int n_in,
                              void* d_out, int out_size, void* d_ws, size_t ws_size,
                              hipStream_t stream) {
  const float* h     = (const float*)d_in[0];
  const float* mask  = (const float*)d_in[1];
  const float* Wqkvz = (const float*)d_in[2];
  const float* Wba   = (const float*)d_in[3];
  const float* ck    = (const float*)d_in[4];
  const float* Alog  = (const float*)d_in[5];
  const float* dtb   = (const float*)d_in[6];
  const float* nk    = (const float*)d_in[7];
  const float* Wout  = (const float*)d_in[8];
  float* out = (float*)d_out;

  char* w = (char*)d_ws;
  const size_t o_qkvz = 0;                         // 100,663,296  [gemm1 .. gate]
  const size_t o_A1   = 100663296;                 //  16,777,216  [amask .. gemm1]
  const size_t o_Bt1  = o_A1 + 16777216;           //  50,331,648  [transpose .. gemm1]
  const size_t o_ba   = o_Bt1 + 50331648;          //   1,048,576
  const size_t o_g    = o_ba + 1048576;            //     524,288
  const size_t o_bt   = o_g + 524288;              //     524,288
  const size_t total  = o_bt + 524288;             // 169,869,312 B = 162 MiB
  if (ws_size < total) return;

  _Float16* qkvz16 = (_Float16*)(w + o_qkvz);
  _Float16* A1     = (_Float16*)(w + o_A1);
  _Float16* Bt1    = (_Float16*)(w + o_Bt1);
  float*    ba32   = (float*)   (w + o_ba);
  float*    gbuf   = (float*)   (w + o_g);
  float*    btb    = (float*)   (w + o_bt);
  // aliases over dead regions:
  _Float16* qn16 = (_Float16*)(w + o_A1);                    // over A1 (dead after gemm1)
  _Float16* kn16 = (_Float16*)(w + o_Bt1);                   // over Bt1[0:16M)
  _Float16* vb16 = (_Float16*)(w + o_Bt1 + 16777216);        // over Bt1[16M:50M); o in-place
  _Float16* Ag   = (_Float16*)(w + o_A1);                    // over qn+kn (dead after scan)
  _Float16* Wt2  = (_Float16*)(w + 0);                       // over qkvz (dead after gate)

  amask_kernel<<<MROWS * HIDD / 4 / 256, 256, 0, stream>>>(h, mask, A1);
  transpose_f16<<<dim3(192, 32), 256, 0, stream>>>(Wqkvz, Bt1, HIDD, NQKV);
  ba_gemm<<<MROWS / 8, 256, 0, stream>>>(h, mask, Wba, ba32);
  gemm8p<_Float16, 256><<<16 * 48, 512, 0, stream>>>(A1, Bt1, qkvz16, MROWS, NQKV, HIDD, 48);
  conv_kernel<<<MROWS, 256, 0, stream>>>(qkvz16, ck, qn16, kn16, vb16);
  egbeta_kernel<<<MROWS * 32 / 256, 256, 0, stream>>>(ba32, Alog, dtb, gbuf, btb);
  chunk_scan<<<256, 512, 0, stream>>>(qn16, kn16, vb16, gbuf, btb);
  gate_kernel<<<MROWS, 256, 0, stream>>>(vb16, qkvz16, nk, Ag);
  transpose_f16<<<dim3(32, 64), 256, 0, stream>>>(Wout, Wt2, 4096, HIDD);
  gemm8p<float, 128><<<32 * 8, 512, 0, stream>>>(Ag, Wt2, out, MROWS, HIDD, 4096, 8);
}